// Round 9
// baseline (3152.735 us; speedup 1.0000x reference)
//
#include <hip/hip_runtime.h>
#include <cstdint>

// ---------------------------------------------------------------------------
// PET full model, round 8 (= round 7 + attn scores in registers).
//   - attn: pl[64][65] LDS (16.6KB) -> float p[64] registers, full unroll.
//     LDS 33.8KB -> 16.9KB => 4 -> 9 blocks/CU. Single-variable change.
//   - Everything else identical to R7 (2,296us measured).
// ---------------------------------------------------------------------------

constexpr int A_ = 2048, N_ = 64, D_ = 256, H_ = 8, L_ = 2, V_ = 119;
constexpr int AN_ = A_ * N_;

typedef unsigned short bf16;
typedef __attribute__((ext_vector_type(4))) unsigned short u16x4;
typedef __attribute__((ext_vector_type(8))) short s16x8;   // MFMA A/B frag
typedef __attribute__((ext_vector_type(4))) float f32x4;   // MFMA C/D frag

__device__ __forceinline__ float bf2f(bf16 u) { return __uint_as_float((unsigned)u << 16); }
__device__ __forceinline__ bf16 f2bf(float f) {
  unsigned u = __float_as_uint(f);
  return (bf16)((u + 0x7fffu + ((u >> 16) & 1u)) >> 16);
}
__device__ __forceinline__ float4 ld4(const float* p) { return *(const float4*)p; }
__device__ __forceinline__ float4 ld4(const bf16* p) {
  u16x4 u = *(const u16x4*)p;
  return make_float4(bf2f(u.x), bf2f(u.y), bf2f(u.z), bf2f(u.w));
}
__device__ __forceinline__ void st4(float* p, float4 v) { *(float4*)p = v; }
__device__ __forceinline__ void st4(bf16* p, float4 v) {
  u16x4 u;
  u.x = f2bf(v.x); u.y = f2bf(v.y); u.z = f2bf(v.z); u.w = f2bf(v.w);
  *(u16x4*)p = u;
}
__device__ __forceinline__ float lds1(const float* p) { return *p; }
__device__ __forceinline__ float lds1(const bf16* p) { return bf2f(*p); }
__device__ __forceinline__ void sts1(float* p, float v) { *p = v; }
__device__ __forceinline__ void sts1(bf16* p, float v) { *p = f2bf(v); }

// gelu(x) = x * sigmoid(2z), z = sqrt(2/pi)(x + 0.044715 x^3)
__device__ __forceinline__ float gelu_f(float x) {
  float z2 = 1.5957691216057308f * x * (1.f + 0.044715f * x * x);  // 2z
  float e = __expf(-z2);
  return x * __builtin_amdgcn_rcpf(1.f + e);
}

__device__ __forceinline__ float wave_sum(float s) {
#pragma unroll
  for (int off = 32; off > 0; off >>= 1) s += __shfl_down(s, off, 64);
  return __shfl(s, 0, 64);
}

__device__ __forceinline__ void gload_lds16(const bf16* g, void* lds) {
  __builtin_amdgcn_global_load_lds(
      (const __attribute__((address_space(1))) unsigned int*)g,
      (__attribute__((address_space(3))) unsigned int*)lds, 16, 0, 0);
}

__global__ void zero_kernel(float* p, int n) {
  int i = blockIdx.x * 256 + threadIdx.x;
  if (i < n) p[i] = 0.f;
}

// W [K][N] f32  ->  Wt [N][K] bf16
__global__ __launch_bounds__(256) void wt_kernel(
    const float* __restrict__ W, bf16* __restrict__ Wt, int K, int N) {
  int idx = blockIdx.x * 256 + threadIdx.x;
  if (idx >= K * N) return;
  int k = idx / N, n = idx - k * N;
  Wt[(size_t)n * K + k] = f2bf(W[idx]);
}

__global__ __launch_bounds__(256) void init_msgs_kernel(
    const int* __restrict__ ns, const float* __restrict__ ne, bf16* __restrict__ msgs) {
  int t = blockIdx.x, d = threadIdx.x;
  msgs[(size_t)t * D_ + d] = f2bf(ne[(size_t)ns[t] * D_ + d]);
}

__global__ __launch_bounds__(256) void gather_nodes_kernel(
    const int* __restrict__ species, const float* __restrict__ node_embed_l,
    float* __restrict__ nodesbuf) {
  int a = blockIdx.x, d = threadIdx.x;
  nodesbuf[(size_t)a * D_ + d] = node_embed_l[(size_t)species[a] * D_ + d];
}

// Fused: x = msgs + gelu(efeat@W_edge + b) + nodes[a];  h = LN1(x)*g + b.
__global__ __launch_bounds__(256) void build_x_ln_kernel(
    const bf16* __restrict__ msgs, const float* __restrict__ ev,
    const float* __restrict__ ed, const float* __restrict__ We,
    const float* __restrict__ be, const float* __restrict__ nodesbuf,
    const float* __restrict__ lng, const float* __restrict__ lnb,
    bf16* __restrict__ x, bf16* __restrict__ h, int token0) {
  int lt = blockIdx.x * 4 + (threadIdx.x >> 6);    // chunk-local token
  int t = token0 + lt;                             // global token
  int lane = threadIdx.x & 63;
  int d4 = lane << 2;
  int a = t >> 6;
  float e0 = ev[(size_t)t * 3 + 0];
  float e1 = ev[(size_t)t * 3 + 1];
  float e2 = ev[(size_t)t * 3 + 2];
  float dd = ed[t];
  float4 m = ld4(msgs + (size_t)t * D_ + d4);
  float4 nb = ld4(nodesbuf + (size_t)a * D_ + d4);
  float4 w0 = ld4(We + d4);
  float4 w1 = ld4(We + D_ + d4);
  float4 w2 = ld4(We + 2 * D_ + d4);
  float4 w3 = ld4(We + 3 * D_ + d4);
  float4 bb = ld4(be + d4);
  float r[4];
  {
    float mm[4] = {m.x, m.y, m.z, m.w};
    float nn[4] = {nb.x, nb.y, nb.z, nb.w};
    float ww0[4] = {w0.x, w0.y, w0.z, w0.w};
    float ww1[4] = {w1.x, w1.y, w1.z, w1.w};
    float ww2[4] = {w2.x, w2.y, w2.z, w2.w};
    float ww3[4] = {w3.x, w3.y, w3.z, w3.w};
    float bbv[4] = {bb.x, bb.y, bb.z, bb.w};
#pragma unroll
    for (int c = 0; c < 4; ++c) {
      float tt = e0 * ww0[c] + e1 * ww1[c] + e2 * ww2[c] + dd * ww3[c] + bbv[c];
      r[c] = mm[c] + gelu_f(tt) + nn[c];
    }
  }
  st4(x + (size_t)lt * D_ + d4, make_float4(r[0], r[1], r[2], r[3]));
  float s = wave_sum(r[0] + r[1] + r[2] + r[3]);
  float mean = s * (1.f / 256.f);
  float c0 = r[0] - mean, c1 = r[1] - mean, c2 = r[2] - mean, c3 = r[3] - mean;
  float q = wave_sum(c0 * c0 + c1 * c1 + c2 * c2 + c3 * c3);
  float rstd = rsqrtf(q * (1.f / 256.f) + 1e-5f);
  float4 g4 = *(const float4*)(lng + d4);
  float4 b4 = *(const float4*)(lnb + d4);
  float4 o;
  o.x = c0 * rstd * g4.x + b4.x;
  o.y = c1 * rstd * g4.y + b4.y;
  o.z = c2 * rstd * g4.z + b4.z;
  o.w = c3 * rstd * g4.w + b4.w;
  st4(h + (size_t)lt * D_ + d4, o);
}

// h = LN(x)*g + b, bf16 out; one wave per row (LN2 path)
__global__ __launch_bounds__(256) void ln_apply_kernel(
    const bf16* __restrict__ x, const float* __restrict__ gw,
    const float* __restrict__ bw, bf16* __restrict__ h) {
  int row = blockIdx.x * 4 + (threadIdx.x >> 6);
  int lane = threadIdx.x & 63;
  float4 v = ld4(x + (size_t)row * D_ + lane * 4);
  float s = wave_sum(v.x + v.y + v.z + v.w);
  float mean = s * (1.f / 256.f);
  float dx = v.x - mean, dy = v.y - mean, dz = v.z - mean, dw = v.w - mean;
  float q = wave_sum(dx * dx + dy * dy + dz * dz + dw * dw);
  float rstd = rsqrtf(q * (1.f / 256.f) + 1e-5f);
  float4 g4 = *(const float4*)(gw + lane * 4);
  float4 b4 = *(const float4*)(bw + lane * 4);
  float4 o;
  o.x = dx * rstd * g4.x + b4.x;
  o.y = dy * rstd * g4.y + b4.y;
  o.z = dz * rstd * g4.z + b4.z;
  o.w = dw * rstd * g4.w + b4.w;
  st4(h + (size_t)row * D_ + lane * 4, o);
}

// ---------------------------------------------------------------------------
// MFMA GEMM: C[M,N] = op(A[M,K]bf16 @ Bt[N,K]bf16^T + bias) (+R)
// ---------------------------------------------------------------------------
template <bool GELU, bool RES, typename TC>
__global__ __launch_bounds__(256) void mfma_gemm_kernel(
    const bf16* __restrict__ A, const bf16* __restrict__ Bt,
    const float* __restrict__ bias, const TC* __restrict__ Rp, TC* __restrict__ Cp,
    int M, int N, int K) {
  __shared__ __align__(16) char AlsB[128 * 64];
  __shared__ __align__(16) char BlsB[128 * 64];
  const int nb = N >> 7;
  const int bx = blockIdx.x % nb;
  const int by = blockIdx.x / nb;
  const int tid = threadIdx.x;
  const int w = tid >> 6, l = tid & 63;
  const int wm = w >> 1, wn = w & 1;
  const int srow = l >> 2;
  const int kg = (l & 3) ^ ((l >> 3) & 3);
  const bf16* Ag = A + (size_t)(by * 128 + w * 32 + srow) * K + kg * 8;
  const bf16* Bg = Bt + (size_t)(bx * 128 + w * 32 + srow) * K + kg * 8;
  char* AlsW = AlsB + w * 2048;
  char* BlsW = BlsB + w * 2048;
  const int frow = l & 15;
  const int soff = (((l >> 4) ^ ((l >> 1) & 3)) << 4);
  const char* Ar = AlsB + (wm * 64 + frow) * 64 + soff;
  const char* Br = BlsB + (wn * 64 + frow) * 64 + soff;

  f32x4 acc[4][4] = {};
  for (int k0 = 0; k0 < K; k0 += 32) {
    __syncthreads();
    gload_lds16(Ag + k0, AlsW);
    gload_lds16(Ag + (size_t)16 * K + k0, AlsW + 1024);
    gload_lds16(Bg + k0, BlsW);
    gload_lds16(Bg + (size_t)16 * K + k0, BlsW + 1024);
    __syncthreads();
    s16x8 af[4], bfr[4];
#pragma unroll
    for (int mi = 0; mi < 4; ++mi) af[mi] = *(const s16x8*)(Ar + mi * 1024);
#pragma unroll
    for (int nj = 0; nj < 4; ++nj) bfr[nj] = *(const s16x8*)(Br + nj * 1024);
#pragma unroll
    for (int mi = 0; mi < 4; ++mi)
#pragma unroll
      for (int nj = 0; nj < 4; ++nj)
        acc[mi][nj] = __builtin_amdgcn_mfma_f32_16x16x32_bf16(af[mi], bfr[nj],
                                                              acc[mi][nj], 0, 0, 0);
  }
  const int r0 = (l >> 4) << 2;
#pragma unroll
  for (int mi = 0; mi < 4; ++mi) {
    int rowb = by * 128 + wm * 64 + mi * 16 + r0;
#pragma unroll
    for (int r = 0; r < 4; ++r) {
      size_t rowoff = (size_t)(rowb + r) * N;
#pragma unroll
      for (int nj = 0; nj < 4; ++nj) {
        int col = bx * 128 + wn * 64 + nj * 16 + frow;
        float v = acc[mi][nj][r] + bias[col];
        if constexpr (GELU) v = gelu_f(v);
        if constexpr (RES) v += lds1(Rp + rowoff + col);
        sts1(Cp + rowoff + col, v);
      }
    }
  }
}

// Edge head fused: edge_e[row] += sum_col gelu(x@WehT + beh)[row,col] * wef[col]
__global__ __launch_bounds__(256) void edge_head_kernel(
    const bf16* __restrict__ A, const bf16* __restrict__ Bt,
    const float* __restrict__ bias, const float* __restrict__ wef,
    float* __restrict__ edge_e, int M, int N, int K) {
  __shared__ __align__(16) char AlsB[128 * 64];
  __shared__ __align__(16) char BlsB[128 * 64];
  const int nb = N >> 7;
  const int bx = blockIdx.x % nb;
  const int by = blockIdx.x / nb;
  const int tid = threadIdx.x;
  const int w = tid >> 6, l = tid & 63;
  const int wm = w >> 1, wn = w & 1;
  const int srow = l >> 2;
  const int kg = (l & 3) ^ ((l >> 3) & 3);
  const bf16* Ag = A + (size_t)(by * 128 + w * 32 + srow) * K + kg * 8;
  const bf16* Bg = Bt + (size_t)(bx * 128 + w * 32 + srow) * K + kg * 8;
  char* AlsW = AlsB + w * 2048;
  char* BlsW = BlsB + w * 2048;
  const int frow = l & 15;
  const int soff = (((l >> 4) ^ ((l >> 1) & 3)) << 4);
  const char* Ar = AlsB + (wm * 64 + frow) * 64 + soff;
  const char* Br = BlsB + (wn * 64 + frow) * 64 + soff;

  f32x4 acc[4][4] = {};
  for (int k0 = 0; k0 < K; k0 += 32) {
    __syncthreads();
    gload_lds16(Ag + k0, AlsW);
    gload_lds16(Ag + (size_t)16 * K + k0, AlsW + 1024);
    gload_lds16(Bg + k0, BlsW);
    gload_lds16(Bg + (size_t)16 * K + k0, BlsW + 1024);
    __syncthreads();
    s16x8 af[4], bfr[4];
#pragma unroll
    for (int mi = 0; mi < 4; ++mi) af[mi] = *(const s16x8*)(Ar + mi * 1024);
#pragma unroll
    for (int nj = 0; nj < 4; ++nj) bfr[nj] = *(const s16x8*)(Br + nj * 1024);
#pragma unroll
    for (int mi = 0; mi < 4; ++mi)
#pragma unroll
      for (int nj = 0; nj < 4; ++nj)
        acc[mi][nj] = __builtin_amdgcn_mfma_f32_16x16x32_bf16(af[mi], bfr[nj],
                                                              acc[mi][nj], 0, 0, 0);
  }
  const int r0 = (l >> 4) << 2;
#pragma unroll
  for (int mi = 0; mi < 4; ++mi) {
#pragma unroll
    for (int r = 0; r < 4; ++r) {
      float s = 0.f;
#pragma unroll
      for (int nj = 0; nj < 4; ++nj) {
        int col = bx * 128 + wn * 64 + nj * 16 + frow;
        s += gelu_f(acc[mi][nj][r] + bias[col]) * wef[col];
      }
      s += __shfl_xor(s, 1, 64);
      s += __shfl_xor(s, 2, 64);
      s += __shfl_xor(s, 4, 64);
      s += __shfl_xor(s, 8, 64);
      if (frow == 0) {
        int row = by * 128 + wm * 64 + mi * 16 + r0 + r;
        atomicAdd(&edge_e[row], s);
      }
    }
  }
}

// fp32 vector GEMM (small node-head chain only)
template <bool GELU, bool RES>
__global__ __launch_bounds__(256) void vgemm_kernel(
    const float* __restrict__ Ap, const float* __restrict__ Bp,
    const float* __restrict__ bias, const float* __restrict__ Rp,
    float* __restrict__ Cp, int M, int N, int K) {
  __shared__ float As[16][65];
  __shared__ float Bs[16][65];
  int nb = N >> 6;
  int bx = blockIdx.x % nb;
  int by = blockIdx.x / nb;
  int tid = threadIdx.x;
  int tx = tid & 15, ty = tid >> 4;
  int am = tid >> 2, akq = (tid & 3) << 2;
  int bk = tid >> 4, bc = (tid & 15) << 2;
  const float* Ab = Ap + (size_t)(by * 64) * K;
  const float* Bb = Bp + bx * 64;
  float acc[4][4] = {};
  for (int k0 = 0; k0 < K; k0 += 16) {
    float4 av = ld4(Ab + (size_t)am * K + k0 + akq);
    As[akq + 0][am] = av.x; As[akq + 1][am] = av.y;
    As[akq + 2][am] = av.z; As[akq + 3][am] = av.w;
    float4 bv4 = ld4(Bb + (size_t)(k0 + bk) * N + bc);
    Bs[bk][bc + 0] = bv4.x; Bs[bk][bc + 1] = bv4.y;
    Bs[bk][bc + 2] = bv4.z; Bs[bk][bc + 3] = bv4.w;
    __syncthreads();
#pragma unroll
    for (int k = 0; k < 16; ++k) {
      float ar[4], br[4];
#pragma unroll
      for (int i = 0; i < 4; ++i) ar[i] = As[k][ty * 4 + i];
#pragma unroll
      for (int j = 0; j < 4; ++j) br[j] = Bs[k][tx * 4 + j];
#pragma unroll
      for (int i = 0; i < 4; ++i)
#pragma unroll
        for (int j = 0; j < 4; ++j) acc[i][j] += ar[i] * br[j];
    }
    __syncthreads();
  }
#pragma unroll
  for (int i = 0; i < 4; ++i) {
    int row = by * 64 + ty * 4 + i;
    int col0 = bx * 64 + tx * 4;
    float4 v = make_float4(acc[i][0], acc[i][1], acc[i][2], acc[i][3]);
    float4 bs = *(const float4*)(bias + col0);
    v.x += bs.x; v.y += bs.y; v.z += bs.z; v.w += bs.w;
    if constexpr (GELU) {
      v.x = gelu_f(v.x); v.y = gelu_f(v.y); v.z = gelu_f(v.z); v.w = gelu_f(v.w);
    }
    if constexpr (RES) {
      float4 r = ld4(Rp + (size_t)row * N + col0);
      v.x += r.x; v.y += r.y; v.z += r.z; v.w += r.w;
    }
    st4(Cp + (size_t)row * N + col0, v);
  }
}

// one wave per (chunk-local atom, head); scores in REGISTERS (LDS 16.9KB)
__global__ __launch_bounds__(64) void attn_kernel(
    const bf16* __restrict__ qkv, const float* __restrict__ cutoff,
    const unsigned char* __restrict__ mask, bf16* __restrict__ out, int atom0) {
  int al = blockIdx.x >> 3;
  int h = blockIdx.x & 7;
  int a = atom0 + al;
  int lane = threadIdx.x;
  __shared__ float kl[64][32];
  __shared__ float vl[64][32];
  __shared__ float cw[64];
  __shared__ float mk[64];
  const bf16* base = qkv + (size_t)al * (64 * 768);
#pragma unroll
  for (int it = 0; it < 8; ++it) {
    int li = it * 64 + lane;
    int row = li >> 3, d4 = (li & 7) << 2;
    *(float4*)&kl[row][d4] = ld4(base + (size_t)row * 768 + 256 + h * 32 + d4);
    *(float4*)&vl[row][d4] = ld4(base + (size_t)row * 768 + 512 + h * 32 + d4);
  }
  {
    int t = a * 64 + lane;
    cw[lane] = cutoff[t];
    mk[lane] = mask[t] ? 1.f : 0.f;
  }
  float4 q[8];
  const bf16* qrow = base + (size_t)lane * 768 + h * 32;
#pragma unroll
  for (int i = 0; i < 8; ++i) q[i] = ld4(qrow + i * 4);
  __syncthreads();
  const float inv = 0.17677669529663687f;  // 1/sqrt(32)
  float p[64];
  float mx = -3e38f;
#pragma unroll
  for (int j = 0; j < 64; ++j) {
    float s = 0.f;
#pragma unroll
    for (int i = 0; i < 8; ++i) {
      float4 kk = *(float4*)&kl[j][i * 4];
      s += q[i].x * kk.x + q[i].y * kk.y + q[i].z * kk.z + q[i].w * kk.w;
    }
    s *= inv;
    if (mk[j] != 0.f) s = -1e9f;
    p[j] = s;
    mx = fmaxf(mx, s);
  }
  float denom = 0.f;
#pragma unroll
  for (int j = 0; j < 64; ++j) {
    float e = __expf(p[j] - mx);
    p[j] = e;
    denom += e;
  }
  float sc = __builtin_amdgcn_rcpf(denom);
#pragma unroll
  for (int j = 0; j < 64; ++j) p[j] *= sc * cw[j];
  float4 o[8] = {};
#pragma unroll
  for (int j = 0; j < 64; ++j) {
    float pj = p[j];
#pragma unroll
    for (int i = 0; i < 8; ++i) {
      float4 vv = *(float4*)&vl[j][i * 4];
      o[i].x += pj * vv.x; o[i].y += pj * vv.y; o[i].z += pj * vv.z; o[i].w += pj * vv.w;
    }
  }
  bf16* orow = out + (size_t)(al * 64 + lane) * D_ + h * 32;
#pragma unroll
  for (int i = 0; i < 8; ++i) st4(orow + i * 4, o[i]);
}

// pooled[a,:] = sum_n x[a,n,:] * (mask?0:cutoff)
__global__ __launch_bounds__(256) void pooled_kernel(
    const bf16* __restrict__ x, const float* __restrict__ cutoff,
    const unsigned char* __restrict__ mask, float* __restrict__ p0) {
  int a = blockIdx.x, d = threadIdx.x;
  __shared__ float w[64];
  if (d < 64) {
    int t = a * 64 + d;
    w[d] = mask[t] ? 0.f : cutoff[t];
  }
  __syncthreads();
  float acc = 0.f;
  const bf16* xb = x + (size_t)a * 64 * D_ + d;
#pragma unroll 8
  for (int n = 0; n < 64; ++n) acc += bf2f(xb[(size_t)n * D_]) * w[n];
  p0[(size_t)a * D_ + d] = acc;
}

template <typename TA>
__global__ __launch_bounds__(256) void rowdot_kernel(
    const TA* __restrict__ Ap, const float* __restrict__ w,
    const float* __restrict__ biasp, const unsigned char* __restrict__ mask,
    float* __restrict__ outp) {
  int row = blockIdx.x * 4 + (threadIdx.x >> 6);
  int lane = threadIdx.x & 63;
  float4 v = ld4(Ap + (size_t)row * D_ + lane * 4);
  float4 ww = *(const float4*)(w + lane * 4);
  float s = wave_sum(v.x * ww.x + v.y * ww.y + v.z * ww.z + v.w * ww.w);
  if (lane == 0) {
    float e = s + biasp[0];
    if (mask && mask[row]) e = 0.f;
    outp[row] = e;
  }
}

// energies[a] += node_e[a] + sum_n (mask?0:(edge_e+bef)) * cutoff
__global__ __launch_bounds__(64) void accum_energy_kernel(
    const float* __restrict__ node_e, const float* __restrict__ edge_e,
    const float* __restrict__ befp, const unsigned char* __restrict__ mask,
    const float* __restrict__ cutoff, float* __restrict__ energies) {
  int a = blockIdx.x, n = threadIdx.x;
  int t = a * 64 + n;
  float e = mask[t] ? 0.f : (edge_e[t] + befp[0]);
  float s = wave_sum(e * cutoff[t]);
  if (n == 0) energies[a] += node_e[a] + s;
}

__global__ __launch_bounds__(256) void rev_mix_kernel(
    const bf16* __restrict__ x, const int* __restrict__ rev,
    const unsigned char* __restrict__ mask, bf16* __restrict__ msgs) {
  size_t tid = (size_t)blockIdx.x * 256 + threadIdx.x;
  int token = int(tid >> 6);
  int d4 = int(tid & 63) << 2;
  int src = rev[token];
  float4 r = make_float4(0.f, 0.f, 0.f, 0.f);
  if (!mask[token] && !mask[src]) r = ld4(x + (size_t)src * D_ + d4);
  float4 m = ld4(msgs + (size_t)token * D_ + d4);
  m.x = 0.5f * (m.x + r.x);
  m.y = 0.5f * (m.y + r.y);
  m.z = 0.5f * (m.z + r.z);
  m.w = 0.5f * (m.w + r.w);
  st4(msgs + (size_t)token * D_ + d4, m);
}

extern "C" void kernel_launch(void* const* d_in, const int* in_sizes, int n_in,
                              void* d_out, int out_size, void* d_ws, size_t ws_size,
                              hipStream_t stream) {
  const int* species = (const int*)d_in[0];
  const int* nspecies = (const int*)d_in[1];
  const float* ev = (const float*)d_in[2];
  const float* ed = (const float*)d_in[3];
  const unsigned char* mask = (const unsigned char*)d_in[4];
  const int* rev = (const int*)d_in[5];
  const float* cutoff = (const float*)d_in[6];
  const float* node_embed = (const float*)d_in[7];
  const float* neigh_embed = (const float*)d_in[8];
  const float* W_edge = (const float*)d_in[9];
  const float* b_edge = (const float*)d_in[10];
  const float* ln1_g = (const float*)d_in[11];
  const float* ln1_b = (const float*)d_in[12];
  const float* Wqkv = (const float*)d_in[13];
  const float* bqkv = (const float*)d_in[14];
  const float* Wo = (const float*)d_in[15];
  const float* bo = (const float*)d_in[16];
  const float* ln2_g = (const float*)d_in[17];
  const float* ln2_b = (const float*)d_in[18];
  const float* Wff1 = (const float*)d_in[19];
  const float* bff1 = (const float*)d_in[20];
  const float* Wff2 = (const float*)d_in[21];
  const float* bff2 = (const float*)d_in[22];
  const float* Wnode = (const float*)d_in[23];
  const float* bnode = (const float*)d_in[24];
  const float* Wnh = (const float*)d_in[25];
  const float* bnh = (const float*)d_in[26];
  const float* Wnf = (const float*)d_in[27];
  const float* bnf = (const float*)d_in[28];
  const float* Weh = (const float*)d_in[29];
  const float* beh = (const float*)d_in[30];
  const float* Wef = (const float*)d_in[31];
  const float* bef = (const float*)d_in[32];
  float* out = (float*)d_out;

  // adaptive chunk count (exact footprints: CH2=308MB, CH4=224MB, CH8=182MB)
  int CHv = 8;
  if (ws_size >= (size_t)330000000) CHv = 2;
  else if (ws_size >= (size_t)240000000) CHv = 4;
  const int RW = AN_ / CHv;    // tokens per chunk
  const int ATC = A_ / CHv;    // atoms per chunk

  char* wsb = (char*)d_ws;
  size_t off = 0;
  auto alloc = [&](size_t bytes) {
    void* p = wsb + off;
    off += (bytes + 255) & ~(size_t)255;
    return p;
  };
  bf16* msgs = (bf16*)alloc((size_t)AN_ * D_ * 2);     // 67 MB
  bf16* x = (bf16*)alloc((size_t)AN_ * D_ * 2);        // 67 MB
  bf16* U1 = (bf16*)alloc((size_t)RW * D_ * 2);        // h / attn-out chunk
  bf16* U2 = (bf16*)alloc((size_t)RW * 1024 * 2);      // qkv / ff-hidden chunk
  bf16* WqkvT = (bf16*)alloc((size_t)L_ * 768 * 256 * 2);
  bf16* WoT = (bf16*)alloc((size_t)L_ * 256 * 256 * 2);
  bf16* Wff1T = (bf16*)alloc((size_t)L_ * 1024 * 256 * 2);
  bf16* Wff2T = (bf16*)alloc((size_t)L_ * 256 * 1024 * 2);
  bf16* WehT = (bf16*)alloc((size_t)L_ * 256 * 256 * 2);
  float* nodesbuf = (float*)alloc((size_t)A_ * D_ * 4);
  float* node_e = (float*)alloc((size_t)A_ * 4);
  float* edge_e = (float*)alloc((size_t)AN_ * 4);
  // node-head scratch aliased into U2 (dead during node-head phase)
  float* p0 = (float*)U2;
  float* p1 = p0 + (size_t)A_ * D_;
  float* p2 = p1 + (size_t)A_ * D_;
  (void)in_sizes; (void)n_in; (void)out_size;

  for (int l = 0; l < L_; ++l) {
    wt_kernel<<<(256 * 768 + 255) / 256, 256, 0, stream>>>(
        Wqkv + (size_t)l * 256 * 768, WqkvT + (size_t)l * 768 * 256, 256, 768);
    wt_kernel<<<(256 * 256 + 255) / 256, 256, 0, stream>>>(
        Wo + (size_t)l * 256 * 256, WoT + (size_t)l * 256 * 256, 256, 256);
    wt_kernel<<<(256 * 1024 + 255) / 256, 256, 0, stream>>>(
        Wff1 + (size_t)l * 256 * 1024, Wff1T + (size_t)l * 1024 * 256, 256, 1024);
    wt_kernel<<<(1024 * 256 + 255) / 256, 256, 0, stream>>>(
        Wff2 + (size_t)l * 1024 * 256, Wff2T + (size_t)l * 256 * 1024, 1024, 256);
    wt_kernel<<<(256 * 256 + 255) / 256, 256, 0, stream>>>(
        Weh + (size_t)l * 256 * 256, WehT + (size_t)l * 256 * 256, 256, 256);
  }

  zero_kernel<<<(A_ + 255) / 256, 256, 0, stream>>>(out, A_);
  init_msgs_kernel<<<AN_, 256, 0, stream>>>(nspecies, neigh_embed, msgs);

  for (int l = 0; l < L_; ++l) {
    gather_nodes_kernel<<<A_, 256, 0, stream>>>(
        species, node_embed + (size_t)l * V_ * D_, nodesbuf);
    // --- attention block (chunked; build_x + LN1 fused per chunk) ---
    for (int c = 0; c < CHv; ++c) {
      bf16* xc = x + (size_t)c * RW * D_;
      build_x_ln_kernel<<<RW / 4, 256, 0, stream>>>(
          msgs, ev, ed, W_edge + (size_t)l * 4 * D_, b_edge + (size_t)l * D_,
          nodesbuf, ln1_g + (size_t)l * D_, ln1_b + (size_t)l * D_,
          xc, U1, c * RW);
      mfma_gemm_kernel<false, false, bf16><<<(RW / 128) * (768 / 128), 256, 0, stream>>>(
          U1, WqkvT + (size_t)l * 768 * 256, bqkv + (size_t)l * 768, (const bf16*)nullptr,
          U2, RW, 768, 256);
      attn_kernel<<<ATC * H_, 64, 0, stream>>>(U2, cutoff, mask, U1, c * ATC);
      mfma_gemm_kernel<false, true, bf16><<<(RW / 128) * (256 / 128), 256, 0, stream>>>(
          U1, WoT + (size_t)l * 256 * 256, bo + (size_t)l * D_, xc, xc, RW, 256, 256);
    }
    // --- FF block (chunked) ---
    for (int c = 0; c < CHv; ++c) {
      bf16* xc = x + (size_t)c * RW * D_;
      ln_apply_kernel<<<RW / 4, 256, 0, stream>>>(
          xc, ln2_g + (size_t)l * D_, ln2_b + (size_t)l * D_, U1);
      mfma_gemm_kernel<true, false, bf16><<<(RW / 128) * (1024 / 128), 256, 0, stream>>>(
          U1, Wff1T + (size_t)l * 1024 * 256, bff1 + (size_t)l * 1024, (const bf16*)nullptr,
          U2, RW, 1024, 256);
      mfma_gemm_kernel<false, true, bf16><<<(RW / 128) * (256 / 128), 256, 0, stream>>>(
          U2, Wff2T + (size_t)l * 256 * 1024, bff2 + (size_t)l * D_, xc, xc,
          RW, 256, 1024);
    }
    // --- node pooling + node energy head (f32 vector, small; scratch in U2) ---
    pooled_kernel<<<A_, 256, 0, stream>>>(x, cutoff, mask, p0);
    vgemm_kernel<false, true><<<(A_ / 64) * (256 / 64), 256, 0, stream>>>(
        p0, Wnode + (size_t)l * D_ * D_, bnode + (size_t)l * D_, nodesbuf, p1,
        A_, 256, 256);
    vgemm_kernel<true, false><<<(A_ / 64) * (256 / 64), 256, 0, stream>>>(
        p1, Wnh + (size_t)l * D_ * D_, bnh + (size_t)l * D_, nullptr, p2, A_, 256, 256);
    rowdot_kernel<float><<<A_ / 4, 256, 0, stream>>>(
        p2, Wnf + (size_t)l * D_, bnf + l, nullptr, node_e);
    // --- edge energy head: fused GEMM+dot, one dispatch over full x ---
    zero_kernel<<<(AN_ + 255) / 256, 256, 0, stream>>>(edge_e, AN_);
    edge_head_kernel<<<(AN_ / 128) * (256 / 128), 256, 0, stream>>>(
        x, WehT + (size_t)l * 256 * 256, beh + (size_t)l * D_, Wef + (size_t)l * D_,
        edge_e, AN_, 256, 256);
    accum_energy_kernel<<<A_, 64, 0, stream>>>(node_e, edge_e, bef + l, mask, cutoff, out);
    // --- reverse message mixing ---
    rev_mix_kernel<<<AN_ * 64 / 256, 256, 0, stream>>>(x, rev, mask, msgs);
  }
}

// Round 10
// 2670.246 us; speedup vs baseline: 1.1807x; 1.1807x over previous
//
#include <hip/hip_runtime.h>
#include <cstdint>

// ---------------------------------------------------------------------------
// PET full model, round 9 (= R7 base + two-pass score-free attention).
//   - R8 post-mortem: p[64] registers spilled (VGPR 256, WRITE 166MB). Fix:
//     store NO scores. Pass1 = max only; pass2 = recompute dot, exp,
//     accumulate o += e*cw*v and denom, scale by rcp(denom) at end.
//     LDS 16.9KB (no pl), VGPR ~140 -> ~9 blocks/CU without spill.
//   - Everything else identical to R7 (2,296us measured).
// ---------------------------------------------------------------------------

constexpr int A_ = 2048, N_ = 64, D_ = 256, H_ = 8, L_ = 2, V_ = 119;
constexpr int AN_ = A_ * N_;

typedef unsigned short bf16;
typedef __attribute__((ext_vector_type(4))) unsigned short u16x4;
typedef __attribute__((ext_vector_type(8))) short s16x8;   // MFMA A/B frag
typedef __attribute__((ext_vector_type(4))) float f32x4;   // MFMA C/D frag

__device__ __forceinline__ float bf2f(bf16 u) { return __uint_as_float((unsigned)u << 16); }
__device__ __forceinline__ bf16 f2bf(float f) {
  unsigned u = __float_as_uint(f);
  return (bf16)((u + 0x7fffu + ((u >> 16) & 1u)) >> 16);
}
__device__ __forceinline__ float4 ld4(const float* p) { return *(const float4*)p; }
__device__ __forceinline__ float4 ld4(const bf16* p) {
  u16x4 u = *(const u16x4*)p;
  return make_float4(bf2f(u.x), bf2f(u.y), bf2f(u.z), bf2f(u.w));
}
__device__ __forceinline__ void st4(float* p, float4 v) { *(float4*)p = v; }
__device__ __forceinline__ void st4(bf16* p, float4 v) {
  u16x4 u;
  u.x = f2bf(v.x); u.y = f2bf(v.y); u.z = f2bf(v.z); u.w = f2bf(v.w);
  *(u16x4*)p = u;
}
__device__ __forceinline__ float lds1(const float* p) { return *p; }
__device__ __forceinline__ float lds1(const bf16* p) { return bf2f(*p); }
__device__ __forceinline__ void sts1(float* p, float v) { *p = v; }
__device__ __forceinline__ void sts1(bf16* p, float v) { *p = f2bf(v); }

// gelu(x) = x * sigmoid(2z), z = sqrt(2/pi)(x + 0.044715 x^3)
__device__ __forceinline__ float gelu_f(float x) {
  float z2 = 1.5957691216057308f * x * (1.f + 0.044715f * x * x);  // 2z
  float e = __expf(-z2);
  return x * __builtin_amdgcn_rcpf(1.f + e);
}

__device__ __forceinline__ float wave_sum(float s) {
#pragma unroll
  for (int off = 32; off > 0; off >>= 1) s += __shfl_down(s, off, 64);
  return __shfl(s, 0, 64);
}

__device__ __forceinline__ void gload_lds16(const bf16* g, void* lds) {
  __builtin_amdgcn_global_load_lds(
      (const __attribute__((address_space(1))) unsigned int*)g,
      (__attribute__((address_space(3))) unsigned int*)lds, 16, 0, 0);
}

__global__ void zero_kernel(float* p, int n) {
  int i = blockIdx.x * 256 + threadIdx.x;
  if (i < n) p[i] = 0.f;
}

// W [K][N] f32  ->  Wt [N][K] bf16
__global__ __launch_bounds__(256) void wt_kernel(
    const float* __restrict__ W, bf16* __restrict__ Wt, int K, int N) {
  int idx = blockIdx.x * 256 + threadIdx.x;
  if (idx >= K * N) return;
  int k = idx / N, n = idx - k * N;
  Wt[(size_t)n * K + k] = f2bf(W[idx]);
}

__global__ __launch_bounds__(256) void init_msgs_kernel(
    const int* __restrict__ ns, const float* __restrict__ ne, bf16* __restrict__ msgs) {
  int t = blockIdx.x, d = threadIdx.x;
  msgs[(size_t)t * D_ + d] = f2bf(ne[(size_t)ns[t] * D_ + d]);
}

__global__ __launch_bounds__(256) void gather_nodes_kernel(
    const int* __restrict__ species, const float* __restrict__ node_embed_l,
    float* __restrict__ nodesbuf) {
  int a = blockIdx.x, d = threadIdx.x;
  nodesbuf[(size_t)a * D_ + d] = node_embed_l[(size_t)species[a] * D_ + d];
}

// Fused: x = msgs + gelu(efeat@W_edge + b) + nodes[a];  h = LN1(x)*g + b.
__global__ __launch_bounds__(256) void build_x_ln_kernel(
    const bf16* __restrict__ msgs, const float* __restrict__ ev,
    const float* __restrict__ ed, const float* __restrict__ We,
    const float* __restrict__ be, const float* __restrict__ nodesbuf,
    const float* __restrict__ lng, const float* __restrict__ lnb,
    bf16* __restrict__ x, bf16* __restrict__ h, int token0) {
  int lt = blockIdx.x * 4 + (threadIdx.x >> 6);    // chunk-local token
  int t = token0 + lt;                             // global token
  int lane = threadIdx.x & 63;
  int d4 = lane << 2;
  int a = t >> 6;
  float e0 = ev[(size_t)t * 3 + 0];
  float e1 = ev[(size_t)t * 3 + 1];
  float e2 = ev[(size_t)t * 3 + 2];
  float dd = ed[t];
  float4 m = ld4(msgs + (size_t)t * D_ + d4);
  float4 nb = ld4(nodesbuf + (size_t)a * D_ + d4);
  float4 w0 = ld4(We + d4);
  float4 w1 = ld4(We + D_ + d4);
  float4 w2 = ld4(We + 2 * D_ + d4);
  float4 w3 = ld4(We + 3 * D_ + d4);
  float4 bb = ld4(be + d4);
  float r[4];
  {
    float mm[4] = {m.x, m.y, m.z, m.w};
    float nn[4] = {nb.x, nb.y, nb.z, nb.w};
    float ww0[4] = {w0.x, w0.y, w0.z, w0.w};
    float ww1[4] = {w1.x, w1.y, w1.z, w1.w};
    float ww2[4] = {w2.x, w2.y, w2.z, w2.w};
    float ww3[4] = {w3.x, w3.y, w3.z, w3.w};
    float bbv[4] = {bb.x, bb.y, bb.z, bb.w};
#pragma unroll
    for (int c = 0; c < 4; ++c) {
      float tt = e0 * ww0[c] + e1 * ww1[c] + e2 * ww2[c] + dd * ww3[c] + bbv[c];
      r[c] = mm[c] + gelu_f(tt) + nn[c];
    }
  }
  st4(x + (size_t)lt * D_ + d4, make_float4(r[0], r[1], r[2], r[3]));
  float s = wave_sum(r[0] + r[1] + r[2] + r[3]);
  float mean = s * (1.f / 256.f);
  float c0 = r[0] - mean, c1 = r[1] - mean, c2 = r[2] - mean, c3 = r[3] - mean;
  float q = wave_sum(c0 * c0 + c1 * c1 + c2 * c2 + c3 * c3);
  float rstd = rsqrtf(q * (1.f / 256.f) + 1e-5f);
  float4 g4 = *(const float4*)(lng + d4);
  float4 b4 = *(const float4*)(lnb + d4);
  float4 o;
  o.x = c0 * rstd * g4.x + b4.x;
  o.y = c1 * rstd * g4.y + b4.y;
  o.z = c2 * rstd * g4.z + b4.z;
  o.w = c3 * rstd * g4.w + b4.w;
  st4(h + (size_t)lt * D_ + d4, o);
}

// h = LN(x)*g + b, bf16 out; one wave per row (LN2 path)
__global__ __launch_bounds__(256) void ln_apply_kernel(
    const bf16* __restrict__ x, const float* __restrict__ gw,
    const float* __restrict__ bw, bf16* __restrict__ h) {
  int row = blockIdx.x * 4 + (threadIdx.x >> 6);
  int lane = threadIdx.x & 63;
  float4 v = ld4(x + (size_t)row * D_ + lane * 4);
  float s = wave_sum(v.x + v.y + v.z + v.w);
  float mean = s * (1.f / 256.f);
  float dx = v.x - mean, dy = v.y - mean, dz = v.z - mean, dw = v.w - mean;
  float q = wave_sum(dx * dx + dy * dy + dz * dz + dw * dw);
  float rstd = rsqrtf(q * (1.f / 256.f) + 1e-5f);
  float4 g4 = *(const float4*)(gw + lane * 4);
  float4 b4 = *(const float4*)(bw + lane * 4);
  float4 o;
  o.x = dx * rstd * g4.x + b4.x;
  o.y = dy * rstd * g4.y + b4.y;
  o.z = dz * rstd * g4.z + b4.z;
  o.w = dw * rstd * g4.w + b4.w;
  st4(h + (size_t)row * D_ + lane * 4, o);
}

// ---------------------------------------------------------------------------
// MFMA GEMM: C[M,N] = op(A[M,K]bf16 @ Bt[N,K]bf16^T + bias) (+R)
// ---------------------------------------------------------------------------
template <bool GELU, bool RES, typename TC>
__global__ __launch_bounds__(256) void mfma_gemm_kernel(
    const bf16* __restrict__ A, const bf16* __restrict__ Bt,
    const float* __restrict__ bias, const TC* __restrict__ Rp, TC* __restrict__ Cp,
    int M, int N, int K) {
  __shared__ __align__(16) char AlsB[128 * 64];
  __shared__ __align__(16) char BlsB[128 * 64];
  const int nb = N >> 7;
  const int bx = blockIdx.x % nb;
  const int by = blockIdx.x / nb;
  const int tid = threadIdx.x;
  const int w = tid >> 6, l = tid & 63;
  const int wm = w >> 1, wn = w & 1;
  const int srow = l >> 2;
  const int kg = (l & 3) ^ ((l >> 3) & 3);
  const bf16* Ag = A + (size_t)(by * 128 + w * 32 + srow) * K + kg * 8;
  const bf16* Bg = Bt + (size_t)(bx * 128 + w * 32 + srow) * K + kg * 8;
  char* AlsW = AlsB + w * 2048;
  char* BlsW = BlsB + w * 2048;
  const int frow = l & 15;
  const int soff = (((l >> 4) ^ ((l >> 1) & 3)) << 4);
  const char* Ar = AlsB + (wm * 64 + frow) * 64 + soff;
  const char* Br = BlsB + (wn * 64 + frow) * 64 + soff;

  f32x4 acc[4][4] = {};
  for (int k0 = 0; k0 < K; k0 += 32) {
    __syncthreads();
    gload_lds16(Ag + k0, AlsW);
    gload_lds16(Ag + (size_t)16 * K + k0, AlsW + 1024);
    gload_lds16(Bg + k0, BlsW);
    gload_lds16(Bg + (size_t)16 * K + k0, BlsW + 1024);
    __syncthreads();
    s16x8 af[4], bfr[4];
#pragma unroll
    for (int mi = 0; mi < 4; ++mi) af[mi] = *(const s16x8*)(Ar + mi * 1024);
#pragma unroll
    for (int nj = 0; nj < 4; ++nj) bfr[nj] = *(const s16x8*)(Br + nj * 1024);
#pragma unroll
    for (int mi = 0; mi < 4; ++mi)
#pragma unroll
      for (int nj = 0; nj < 4; ++nj)
        acc[mi][nj] = __builtin_amdgcn_mfma_f32_16x16x32_bf16(af[mi], bfr[nj],
                                                              acc[mi][nj], 0, 0, 0);
  }
  const int r0 = (l >> 4) << 2;
#pragma unroll
  for (int mi = 0; mi < 4; ++mi) {
    int rowb = by * 128 + wm * 64 + mi * 16 + r0;
#pragma unroll
    for (int r = 0; r < 4; ++r) {
      size_t rowoff = (size_t)(rowb + r) * N;
#pragma unroll
      for (int nj = 0; nj < 4; ++nj) {
        int col = bx * 128 + wn * 64 + nj * 16 + frow;
        float v = acc[mi][nj][r] + bias[col];
        if constexpr (GELU) v = gelu_f(v);
        if constexpr (RES) v += lds1(Rp + rowoff + col);
        sts1(Cp + rowoff + col, v);
      }
    }
  }
}

// Edge head fused: edge_e[row] += sum_col gelu(x@WehT + beh)[row,col] * wef[col]
__global__ __launch_bounds__(256) void edge_head_kernel(
    const bf16* __restrict__ A, const bf16* __restrict__ Bt,
    const float* __restrict__ bias, const float* __restrict__ wef,
    float* __restrict__ edge_e, int M, int N, int K) {
  __shared__ __align__(16) char AlsB[128 * 64];
  __shared__ __align__(16) char BlsB[128 * 64];
  const int nb = N >> 7;
  const int bx = blockIdx.x % nb;
  const int by = blockIdx.x / nb;
  const int tid = threadIdx.x;
  const int w = tid >> 6, l = tid & 63;
  const int wm = w >> 1, wn = w & 1;
  const int srow = l >> 2;
  const int kg = (l & 3) ^ ((l >> 3) & 3);
  const bf16* Ag = A + (size_t)(by * 128 + w * 32 + srow) * K + kg * 8;
  const bf16* Bg = Bt + (size_t)(bx * 128 + w * 32 + srow) * K + kg * 8;
  char* AlsW = AlsB + w * 2048;
  char* BlsW = BlsB + w * 2048;
  const int frow = l & 15;
  const int soff = (((l >> 4) ^ ((l >> 1) & 3)) << 4);
  const char* Ar = AlsB + (wm * 64 + frow) * 64 + soff;
  const char* Br = BlsB + (wn * 64 + frow) * 64 + soff;

  f32x4 acc[4][4] = {};
  for (int k0 = 0; k0 < K; k0 += 32) {
    __syncthreads();
    gload_lds16(Ag + k0, AlsW);
    gload_lds16(Ag + (size_t)16 * K + k0, AlsW + 1024);
    gload_lds16(Bg + k0, BlsW);
    gload_lds16(Bg + (size_t)16 * K + k0, BlsW + 1024);
    __syncthreads();
    s16x8 af[4], bfr[4];
#pragma unroll
    for (int mi = 0; mi < 4; ++mi) af[mi] = *(const s16x8*)(Ar + mi * 1024);
#pragma unroll
    for (int nj = 0; nj < 4; ++nj) bfr[nj] = *(const s16x8*)(Br + nj * 1024);
#pragma unroll
    for (int mi = 0; mi < 4; ++mi)
#pragma unroll
      for (int nj = 0; nj < 4; ++nj)
        acc[mi][nj] = __builtin_amdgcn_mfma_f32_16x16x32_bf16(af[mi], bfr[nj],
                                                              acc[mi][nj], 0, 0, 0);
  }
  const int r0 = (l >> 4) << 2;
#pragma unroll
  for (int mi = 0; mi < 4; ++mi) {
#pragma unroll
    for (int r = 0; r < 4; ++r) {
      float s = 0.f;
#pragma unroll
      for (int nj = 0; nj < 4; ++nj) {
        int col = bx * 128 + wn * 64 + nj * 16 + frow;
        s += gelu_f(acc[mi][nj][r] + bias[col]) * wef[col];
      }
      s += __shfl_xor(s, 1, 64);
      s += __shfl_xor(s, 2, 64);
      s += __shfl_xor(s, 4, 64);
      s += __shfl_xor(s, 8, 64);
      if (frow == 0) {
        int row = by * 128 + wm * 64 + mi * 16 + r0 + r;
        atomicAdd(&edge_e[row], s);
      }
    }
  }
}

// fp32 vector GEMM (small node-head chain only)
template <bool GELU, bool RES>
__global__ __launch_bounds__(256) void vgemm_kernel(
    const float* __restrict__ Ap, const float* __restrict__ Bp,
    const float* __restrict__ bias, const float* __restrict__ Rp,
    float* __restrict__ Cp, int M, int N, int K) {
  __shared__ float As[16][65];
  __shared__ float Bs[16][65];
  int nb = N >> 6;
  int bx = blockIdx.x % nb;
  int by = blockIdx.x / nb;
  int tid = threadIdx.x;
  int tx = tid & 15, ty = tid >> 4;
  int am = tid >> 2, akq = (tid & 3) << 2;
  int bk = tid >> 4, bc = (tid & 15) << 2;
  const float* Ab = Ap + (size_t)(by * 64) * K;
  const float* Bb = Bp + bx * 64;
  float acc[4][4] = {};
  for (int k0 = 0; k0 < K; k0 += 16) {
    float4 av = ld4(Ab + (size_t)am * K + k0 + akq);
    As[akq + 0][am] = av.x; As[akq + 1][am] = av.y;
    As[akq + 2][am] = av.z; As[akq + 3][am] = av.w;
    float4 bv4 = ld4(Bb + (size_t)(k0 + bk) * N + bc);
    Bs[bk][bc + 0] = bv4.x; Bs[bk][bc + 1] = bv4.y;
    Bs[bk][bc + 2] = bv4.z; Bs[bk][bc + 3] = bv4.w;
    __syncthreads();
#pragma unroll
    for (int k = 0; k < 16; ++k) {
      float ar[4], br[4];
#pragma unroll
      for (int i = 0; i < 4; ++i) ar[i] = As[k][ty * 4 + i];
#pragma unroll
      for (int j = 0; j < 4; ++j) br[j] = Bs[k][tx * 4 + j];
#pragma unroll
      for (int i = 0; i < 4; ++i)
#pragma unroll
        for (int j = 0; j < 4; ++j) acc[i][j] += ar[i] * br[j];
    }
    __syncthreads();
  }
#pragma unroll
  for (int i = 0; i < 4; ++i) {
    int row = by * 64 + ty * 4 + i;
    int col0 = bx * 64 + tx * 4;
    float4 v = make_float4(acc[i][0], acc[i][1], acc[i][2], acc[i][3]);
    float4 bs = *(const float4*)(bias + col0);
    v.x += bs.x; v.y += bs.y; v.z += bs.z; v.w += bs.w;
    if constexpr (GELU) {
      v.x = gelu_f(v.x); v.y = gelu_f(v.y); v.z = gelu_f(v.z); v.w = gelu_f(v.w);
    }
    if constexpr (RES) {
      float4 r = ld4(Rp + (size_t)row * N + col0);
      v.x += r.x; v.y += r.y; v.z += r.z; v.w += r.w;
    }
    st4(Cp + (size_t)row * N + col0, v);
  }
}

// one wave per (chunk-local atom, head); TWO-PASS softmax, no score storage.
// LDS = K(8KB) + V(8KB) + cw/mk (0.5KB) = 16.9KB; VGPR ~140 (no p[64]).
__global__ __launch_bounds__(64) void attn_kernel(
    const bf16* __restrict__ qkv, const float* __restrict__ cutoff,
    const unsigned char* __restrict__ mask, bf16* __restrict__ out, int atom0) {
  int al = blockIdx.x >> 3;
  int h = blockIdx.x & 7;
  int a = atom0 + al;
  int lane = threadIdx.x;
  __shared__ float kl[64][32];
  __shared__ float vl[64][32];
  __shared__ float cw[64];
  __shared__ float mk[64];
  const bf16* base = qkv + (size_t)al * (64 * 768);
#pragma unroll
  for (int it = 0; it < 8; ++it) {
    int li = it * 64 + lane;
    int row = li >> 3, d4 = (li & 7) << 2;
    *(float4*)&kl[row][d4] = ld4(base + (size_t)row * 768 + 256 + h * 32 + d4);
    *(float4*)&vl[row][d4] = ld4(base + (size_t)row * 768 + 512 + h * 32 + d4);
  }
  {
    int t = a * 64 + lane;
    cw[lane] = cutoff[t];
    mk[lane] = mask[t] ? 1.f : 0.f;
  }
  float4 q[8];
  const bf16* qrow = base + (size_t)lane * 768 + h * 32;
#pragma unroll
  for (int i = 0; i < 8; ++i) q[i] = ld4(qrow + i * 4);
  __syncthreads();
  const float inv = 0.17677669529663687f;  // 1/sqrt(32)
  // pass 1: row max only (no storage)
  float mx = -3e38f;
  for (int j = 0; j < 64; ++j) {
    float s = 0.f;
#pragma unroll
    for (int i = 0; i < 8; ++i) {
      float4 kk = *(float4*)&kl[j][i * 4];
      s += q[i].x * kk.x + q[i].y * kk.y + q[i].z * kk.z + q[i].w * kk.w;
    }
    s *= inv;
    if (mk[j] != 0.f) s = -1e9f;
    mx = fmaxf(mx, s);
  }
  // pass 2: recompute, exp, accumulate weighted V and denom
  float denom = 0.f;
  float4 o[8] = {};
  for (int j = 0; j < 64; ++j) {
    float s = 0.f;
#pragma unroll
    for (int i = 0; i < 8; ++i) {
      float4 kk = *(float4*)&kl[j][i * 4];
      s += q[i].x * kk.x + q[i].y * kk.y + q[i].z * kk.z + q[i].w * kk.w;
    }
    s *= inv;
    if (mk[j] != 0.f) s = -1e9f;
    float e = __expf(s - mx);
    denom += e;
    float pj = e * cw[j];
#pragma unroll
    for (int i = 0; i < 8; ++i) {
      float4 vv = *(float4*)&vl[j][i * 4];
      o[i].x += pj * vv.x; o[i].y += pj * vv.y; o[i].z += pj * vv.z; o[i].w += pj * vv.w;
    }
  }
  float sc = __builtin_amdgcn_rcpf(denom);
#pragma unroll
  for (int i = 0; i < 8; ++i) {
    o[i].x *= sc; o[i].y *= sc; o[i].z *= sc; o[i].w *= sc;
  }
  bf16* orow = out + (size_t)(al * 64 + lane) * D_ + h * 32;
#pragma unroll
  for (int i = 0; i < 8; ++i) st4(orow + i * 4, o[i]);
}

// pooled[a,:] = sum_n x[a,n,:] * (mask?0:cutoff)
__global__ __launch_bounds__(256) void pooled_kernel(
    const bf16* __restrict__ x, const float* __restrict__ cutoff,
    const unsigned char* __restrict__ mask, float* __restrict__ p0) {
  int a = blockIdx.x, d = threadIdx.x;
  __shared__ float w[64];
  if (d < 64) {
    int t = a * 64 + d;
    w[d] = mask[t] ? 0.f : cutoff[t];
  }
  __syncthreads();
  float acc = 0.f;
  const bf16* xb = x + (size_t)a * 64 * D_ + d;
#pragma unroll 8
  for (int n = 0; n < 64; ++n) acc += bf2f(xb[(size_t)n * D_]) * w[n];
  p0[(size_t)a * D_ + d] = acc;
}

template <typename TA>
__global__ __launch_bounds__(256) void rowdot_kernel(
    const TA* __restrict__ Ap, const float* __restrict__ w,
    const float* __restrict__ biasp, const unsigned char* __restrict__ mask,
    float* __restrict__ outp) {
  int row = blockIdx.x * 4 + (threadIdx.x >> 6);
  int lane = threadIdx.x & 63;
  float4 v = ld4(Ap + (size_t)row * D_ + lane * 4);
  float4 ww = *(const float4*)(w + lane * 4);
  float s = wave_sum(v.x * ww.x + v.y * ww.y + v.z * ww.z + v.w * ww.w);
  if (lane == 0) {
    float e = s + biasp[0];
    if (mask && mask[row]) e = 0.f;
    outp[row] = e;
  }
}

// energies[a] += node_e[a] + sum_n (mask?0:(edge_e+bef)) * cutoff
__global__ __launch_bounds__(64) void accum_energy_kernel(
    const float* __restrict__ node_e, const float* __restrict__ edge_e,
    const float* __restrict__ befp, const unsigned char* __restrict__ mask,
    const float* __restrict__ cutoff, float* __restrict__ energies) {
  int a = blockIdx.x, n = threadIdx.x;
  int t = a * 64 + n;
  float e = mask[t] ? 0.f : (edge_e[t] + befp[0]);
  float s = wave_sum(e * cutoff[t]);
  if (n == 0) energies[a] += node_e[a] + s;
}

__global__ __launch_bounds__(256) void rev_mix_kernel(
    const bf16* __restrict__ x, const int* __restrict__ rev,
    const unsigned char* __restrict__ mask, bf16* __restrict__ msgs) {
  size_t tid = (size_t)blockIdx.x * 256 + threadIdx.x;
  int token = int(tid >> 6);
  int d4 = int(tid & 63) << 2;
  int src = rev[token];
  float4 r = make_float4(0.f, 0.f, 0.f, 0.f);
  if (!mask[token] && !mask[src]) r = ld4(x + (size_t)src * D_ + d4);
  float4 m = ld4(msgs + (size_t)token * D_ + d4);
  m.x = 0.5f * (m.x + r.x);
  m.y = 0.5f * (m.y + r.y);
  m.z = 0.5f * (m.z + r.z);
  m.w = 0.5f * (m.w + r.w);
  st4(msgs + (size_t)token * D_ + d4, m);
}

extern "C" void kernel_launch(void* const* d_in, const int* in_sizes, int n_in,
                              void* d_out, int out_size, void* d_ws, size_t ws_size,
                              hipStream_t stream) {
  const int* species = (const int*)d_in[0];
  const int* nspecies = (const int*)d_in[1];
  const float* ev = (const float*)d_in[2];
  const float* ed = (const float*)d_in[3];
  const unsigned char* mask = (const unsigned char*)d_in[4];
  const int* rev = (const int*)d_in[5];
  const float* cutoff = (const float*)d_in[6];
  const float* node_embed = (const float*)d_in[7];
  const float* neigh_embed = (const float*)d_in[8];
  const float* W_edge = (const float*)d_in[9];
  const float* b_edge = (const float*)d_in[10];
  const float* ln1_g = (const float*)d_in[11];
  const float* ln1_b = (const float*)d_in[12];
  const float* Wqkv = (const float*)d_in[13];
  const float* bqkv = (const float*)d_in[14];
  const float* Wo = (const float*)d_in[15];
  const float* bo = (const float*)d_in[16];
  const float* ln2_g = (const float*)d_in[17];
  const float* ln2_b = (const float*)d_in[18];
  const float* Wff1 = (const float*)d_in[19];
  const float* bff1 = (const float*)d_in[20];
  const float* Wff2 = (const float*)d_in[21];
  const float* bff2 = (const float*)d_in[22];
  const float* Wnode = (const float*)d_in[23];
  const float* bnode = (const float*)d_in[24];
  const float* Wnh = (const float*)d_in[25];
  const float* bnh = (const float*)d_in[26];
  const float* Wnf = (const float*)d_in[27];
  const float* bnf = (const float*)d_in[28];
  const float* Weh = (const float*)d_in[29];
  const float* beh = (const float*)d_in[30];
  const float* Wef = (const float*)d_in[31];
  const float* bef = (const float*)d_in[32];
  float* out = (float*)d_out;

  // adaptive chunk count (exact footprints: CH2=308MB, CH4=224MB, CH8=182MB)
  int CHv = 8;
  if (ws_size >= (size_t)330000000) CHv = 2;
  else if (ws_size >= (size_t)240000000) CHv = 4;
  const int RW = AN_ / CHv;    // tokens per chunk
  const int ATC = A_ / CHv;    // atoms per chunk

  char* wsb = (char*)d_ws;
  size_t off = 0;
  auto alloc = [&](size_t bytes) {
    void* p = wsb + off;
    off += (bytes + 255) & ~(size_t)255;
    return p;
  };
  bf16* msgs = (bf16*)alloc((size_t)AN_ * D_ * 2);     // 67 MB
  bf16* x = (bf16*)alloc((size_t)AN_ * D_ * 2);        // 67 MB
  bf16* U1 = (bf16*)alloc((size_t)RW * D_ * 2);        // h / attn-out chunk
  bf16* U2 = (bf16*)alloc((size_t)RW * 1024 * 2);      // qkv / ff-hidden chunk
  bf16* WqkvT = (bf16*)alloc((size_t)L_ * 768 * 256 * 2);
  bf16* WoT = (bf16*)alloc((size_t)L_ * 256 * 256 * 2);
  bf16* Wff1T = (bf16*)alloc((size_t)L_ * 1024 * 256 * 2);
  bf16* Wff2T = (bf16*)alloc((size_t)L_ * 256 * 1024 * 2);
  bf16* WehT = (bf16*)alloc((size_t)L_ * 256 * 256 * 2);
  float* nodesbuf = (float*)alloc((size_t)A_ * D_ * 4);
  float* node_e = (float*)alloc((size_t)A_ * 4);
  float* edge_e = (float*)alloc((size_t)AN_ * 4);
  // node-head scratch aliased into U2 (dead during node-head phase)
  float* p0 = (float*)U2;
  float* p1 = p0 + (size_t)A_ * D_;
  float* p2 = p1 + (size_t)A_ * D_;
  (void)in_sizes; (void)n_in; (void)out_size;

  for (int l = 0; l < L_; ++l) {
    wt_kernel<<<(256 * 768 + 255) / 256, 256, 0, stream>>>(
        Wqkv + (size_t)l * 256 * 768, WqkvT + (size_t)l * 768 * 256, 256, 768);
    wt_kernel<<<(256 * 256 + 255) / 256, 256, 0, stream>>>(
        Wo + (size_t)l * 256 * 256, WoT + (size_t)l * 256 * 256, 256, 256);
    wt_kernel<<<(256 * 1024 + 255) / 256, 256, 0, stream>>>(
        Wff1 + (size_t)l * 256 * 1024, Wff1T + (size_t)l * 1024 * 256, 256, 1024);
    wt_kernel<<<(1024 * 256 + 255) / 256, 256, 0, stream>>>(
        Wff2 + (size_t)l * 1024 * 256, Wff2T + (size_t)l * 256 * 1024, 1024, 256);
    wt_kernel<<<(256 * 256 + 255) / 256, 256, 0, stream>>>(
        Weh + (size_t)l * 256 * 256, WehT + (size_t)l * 256 * 256, 256, 256);
  }

  zero_kernel<<<(A_ + 255) / 256, 256, 0, stream>>>(out, A_);
  init_msgs_kernel<<<AN_, 256, 0, stream>>>(nspecies, neigh_embed, msgs);

  for (int l = 0; l < L_; ++l) {
    gather_nodes_kernel<<<A_, 256, 0, stream>>>(
        species, node_embed + (size_t)l * V_ * D_, nodesbuf);
    // --- attention block (chunked; build_x + LN1 fused per chunk) ---
    for (int c = 0; c < CHv; ++c) {
      bf16* xc = x + (size_t)c * RW * D_;
      build_x_ln_kernel<<<RW / 4, 256, 0, stream>>>(
          msgs, ev, ed, W_edge + (size_t)l * 4 * D_, b_edge + (size_t)l * D_,
          nodesbuf, ln1_g + (size_t)l * D_, ln1_b + (size_t)l * D_,
          xc, U1, c * RW);
      mfma_gemm_kernel<false, false, bf16><<<(RW / 128) * (768 / 128), 256, 0, stream>>>(
          U1, WqkvT + (size_t)l * 768 * 256, bqkv + (size_t)l * 768, (const bf16*)nullptr,
          U2, RW, 768, 256);
      attn_kernel<<<ATC * H_, 64, 0, stream>>>(U2, cutoff, mask, U1, c * ATC);
      mfma_gemm_kernel<false, true, bf16><<<(RW / 128) * (256 / 128), 256, 0, stream>>>(
          U1, WoT + (size_t)l * 256 * 256, bo + (size_t)l * D_, xc, xc, RW, 256, 256);
    }
    // --- FF block (chunked) ---
    for (int c = 0; c < CHv; ++c) {
      bf16* xc = x + (size_t)c * RW * D_;
      ln_apply_kernel<<<RW / 4, 256, 0, stream>>>(
          xc, ln2_g + (size_t)l * D_, ln2_b + (size_t)l * D_, U1);
      mfma_gemm_kernel<true, false, bf16><<<(RW / 128) * (1024 / 128), 256, 0, stream>>>(
          U1, Wff1T + (size_t)l * 1024 * 256, bff1 + (size_t)l * 1024, (const bf16*)nullptr,
          U2, RW, 1024, 256);
      mfma_gemm_kernel<false, true, bf16><<<(RW / 128) * (256 / 128), 256, 0, stream>>>(
          U2, Wff2T + (size_t)l * 256 * 1024, bff2 + (size_t)l * D_, xc, xc,
          RW, 256, 1024);
    }
    // --- node pooling + node energy head (f32 vector, small; scratch in U2) ---
    pooled_kernel<<<A_, 256, 0, stream>>>(x, cutoff, mask, p0);
    vgemm_kernel<false, true><<<(A_ / 64) * (256 / 64), 256, 0, stream>>>(
        p0, Wnode + (size_t)l * D_ * D_, bnode + (size_t)l * D_, nodesbuf, p1,
        A_, 256, 256);
    vgemm_kernel<true, false><<<(A_ / 64) * (256 / 64), 256, 0, stream>>>(
        p1, Wnh + (size_t)l * D_ * D_, bnh + (size_t)l * D_, nullptr, p2, A_, 256, 256);
    rowdot_kernel<float><<<A_ / 4, 256, 0, stream>>>(
        p2, Wnf + (size_t)l * D_, bnf + l, nullptr, node_e);
    // --- edge energy head: fused GEMM+dot, one dispatch over full x ---
    zero_kernel<<<(AN_ + 255) / 256, 256, 0, stream>>>(edge_e, AN_);
    edge_head_kernel<<<(AN_ / 128) * (256 / 128), 256, 0, stream>>>(
        x, WehT + (size_t)l * 256 * 256, beh + (size_t)l * D_, Wef + (size_t)l * D_,
        edge_e, AN_, 256, 256);
    accum_energy_kernel<<<A_, 64, 0, stream>>>(node_e, edge_e, bef + l, mask, cutoff, out);
    // --- reverse message mixing ---
    rev_mix_kernel<<<AN_ * 64 / 256, 256, 0, stream>>>(x, rev, mask, msgs);
  }
}

// Round 11
// 1923.295 us; speedup vs baseline: 1.6392x; 1.3884x over previous
//
#include <hip/hip_runtime.h>
#include <cstdint>

// ---------------------------------------------------------------------------
// PET full model, round 10 (= R9 base, attention rewritten with MFMA).
//   - attn: per (atom,head) wave. QK^T: Q/K frags direct from global,
//     16x mfma_f32_16x16x32_bf16. Softmax in C-layout (col=lane&15) with
//     shfl_xor(1,2,4,8) row reductions. P->LDS bf16 + V^T->LDS, both with
//     byte ^= (row&7)<<4 swizzle; PV: 16 MFMA. 1/denom applied at O store.
//   - R9 post-mortem: two-pass recompute cost 1.6x with no occupancy win;
//     scalar dot structure was issue-bound -> matrix pipe.
//   - Everything else identical to R9/R7 (measured good).
// ---------------------------------------------------------------------------

constexpr int A_ = 2048, N_ = 64, D_ = 256, H_ = 8, L_ = 2, V_ = 119;
constexpr int AN_ = A_ * N_;

typedef unsigned short bf16;
typedef __attribute__((ext_vector_type(4))) unsigned short u16x4;
typedef __attribute__((ext_vector_type(8))) short s16x8;   // MFMA A/B frag
typedef __attribute__((ext_vector_type(4))) float f32x4;   // MFMA C/D frag

__device__ __forceinline__ float bf2f(bf16 u) { return __uint_as_float((unsigned)u << 16); }
__device__ __forceinline__ bf16 f2bf(float f) {
  unsigned u = __float_as_uint(f);
  return (bf16)((u + 0x7fffu + ((u >> 16) & 1u)) >> 16);
}
__device__ __forceinline__ float4 ld4(const float* p) { return *(const float4*)p; }
__device__ __forceinline__ float4 ld4(const bf16* p) {
  u16x4 u = *(const u16x4*)p;
  return make_float4(bf2f(u.x), bf2f(u.y), bf2f(u.z), bf2f(u.w));
}
__device__ __forceinline__ void st4(float* p, float4 v) { *(float4*)p = v; }
__device__ __forceinline__ void st4(bf16* p, float4 v) {
  u16x4 u;
  u.x = f2bf(v.x); u.y = f2bf(v.y); u.z = f2bf(v.z); u.w = f2bf(v.w);
  *(u16x4*)p = u;
}
__device__ __forceinline__ float lds1(const float* p) { return *p; }
__device__ __forceinline__ float lds1(const bf16* p) { return bf2f(*p); }
__device__ __forceinline__ void sts1(float* p, float v) { *p = v; }
__device__ __forceinline__ void sts1(bf16* p, float v) { *p = f2bf(v); }

// gelu(x) = x * sigmoid(2z), z = sqrt(2/pi)(x + 0.044715 x^3)
__device__ __forceinline__ float gelu_f(float x) {
  float z2 = 1.5957691216057308f * x * (1.f + 0.044715f * x * x);  // 2z
  float e = __expf(-z2);
  return x * __builtin_amdgcn_rcpf(1.f + e);
}

__device__ __forceinline__ float wave_sum(float s) {
#pragma unroll
  for (int off = 32; off > 0; off >>= 1) s += __shfl_down(s, off, 64);
  return __shfl(s, 0, 64);
}

__device__ __forceinline__ void gload_lds16(const bf16* g, void* lds) {
  __builtin_amdgcn_global_load_lds(
      (const __attribute__((address_space(1))) unsigned int*)g,
      (__attribute__((address_space(3))) unsigned int*)lds, 16, 0, 0);
}

__global__ void zero_kernel(float* p, int n) {
  int i = blockIdx.x * 256 + threadIdx.x;
  if (i < n) p[i] = 0.f;
}

// W [K][N] f32  ->  Wt [N][K] bf16
__global__ __launch_bounds__(256) void wt_kernel(
    const float* __restrict__ W, bf16* __restrict__ Wt, int K, int N) {
  int idx = blockIdx.x * 256 + threadIdx.x;
  if (idx >= K * N) return;
  int k = idx / N, n = idx - k * N;
  Wt[(size_t)n * K + k] = f2bf(W[idx]);
}

__global__ __launch_bounds__(256) void init_msgs_kernel(
    const int* __restrict__ ns, const float* __restrict__ ne, bf16* __restrict__ msgs) {
  int t = blockIdx.x, d = threadIdx.x;
  msgs[(size_t)t * D_ + d] = f2bf(ne[(size_t)ns[t] * D_ + d]);
}

__global__ __launch_bounds__(256) void gather_nodes_kernel(
    const int* __restrict__ species, const float* __restrict__ node_embed_l,
    float* __restrict__ nodesbuf) {
  int a = blockIdx.x, d = threadIdx.x;
  nodesbuf[(size_t)a * D_ + d] = node_embed_l[(size_t)species[a] * D_ + d];
}

// Fused: x = msgs + gelu(efeat@W_edge + b) + nodes[a];  h = LN1(x)*g + b.
__global__ __launch_bounds__(256) void build_x_ln_kernel(
    const bf16* __restrict__ msgs, const float* __restrict__ ev,
    const float* __restrict__ ed, const float* __restrict__ We,
    const float* __restrict__ be, const float* __restrict__ nodesbuf,
    const float* __restrict__ lng, const float* __restrict__ lnb,
    bf16* __restrict__ x, bf16* __restrict__ h, int token0) {
  int lt = blockIdx.x * 4 + (threadIdx.x >> 6);    // chunk-local token
  int t = token0 + lt;                             // global token
  int lane = threadIdx.x & 63;
  int d4 = lane << 2;
  int a = t >> 6;
  float e0 = ev[(size_t)t * 3 + 0];
  float e1 = ev[(size_t)t * 3 + 1];
  float e2 = ev[(size_t)t * 3 + 2];
  float dd = ed[t];
  float4 m = ld4(msgs + (size_t)t * D_ + d4);
  float4 nb = ld4(nodesbuf + (size_t)a * D_ + d4);
  float4 w0 = ld4(We + d4);
  float4 w1 = ld4(We + D_ + d4);
  float4 w2 = ld4(We + 2 * D_ + d4);
  float4 w3 = ld4(We + 3 * D_ + d4);
  float4 bb = ld4(be + d4);
  float r[4];
  {
    float mm[4] = {m.x, m.y, m.z, m.w};
    float nn[4] = {nb.x, nb.y, nb.z, nb.w};
    float ww0[4] = {w0.x, w0.y, w0.z, w0.w};
    float ww1[4] = {w1.x, w1.y, w1.z, w1.w};
    float ww2[4] = {w2.x, w2.y, w2.z, w2.w};
    float ww3[4] = {w3.x, w3.y, w3.z, w3.w};
    float bbv[4] = {bb.x, bb.y, bb.z, bb.w};
#pragma unroll
    for (int c = 0; c < 4; ++c) {
      float tt = e0 * ww0[c] + e1 * ww1[c] + e2 * ww2[c] + dd * ww3[c] + bbv[c];
      r[c] = mm[c] + gelu_f(tt) + nn[c];
    }
  }
  st4(x + (size_t)lt * D_ + d4, make_float4(r[0], r[1], r[2], r[3]));
  float s = wave_sum(r[0] + r[1] + r[2] + r[3]);
  float mean = s * (1.f / 256.f);
  float c0 = r[0] - mean, c1 = r[1] - mean, c2 = r[2] - mean, c3 = r[3] - mean;
  float q = wave_sum(c0 * c0 + c1 * c1 + c2 * c2 + c3 * c3);
  float rstd = rsqrtf(q * (1.f / 256.f) + 1e-5f);
  float4 g4 = *(const float4*)(lng + d4);
  float4 b4 = *(const float4*)(lnb + d4);
  float4 o;
  o.x = c0 * rstd * g4.x + b4.x;
  o.y = c1 * rstd * g4.y + b4.y;
  o.z = c2 * rstd * g4.z + b4.z;
  o.w = c3 * rstd * g4.w + b4.w;
  st4(h + (size_t)lt * D_ + d4, o);
}

// h = LN(x)*g + b, bf16 out; one wave per row (LN2 path)
__global__ __launch_bounds__(256) void ln_apply_kernel(
    const bf16* __restrict__ x, const float* __restrict__ gw,
    const float* __restrict__ bw, bf16* __restrict__ h) {
  int row = blockIdx.x * 4 + (threadIdx.x >> 6);
  int lane = threadIdx.x & 63;
  float4 v = ld4(x + (size_t)row * D_ + lane * 4);
  float s = wave_sum(v.x + v.y + v.z + v.w);
  float mean = s * (1.f / 256.f);
  float dx = v.x - mean, dy = v.y - mean, dz = v.z - mean, dw = v.w - mean;
  float q = wave_sum(dx * dx + dy * dy + dz * dz + dw * dw);
  float rstd = rsqrtf(q * (1.f / 256.f) + 1e-5f);
  float4 g4 = *(const float4*)(gw + lane * 4);
  float4 b4 = *(const float4*)(bw + lane * 4);
  float4 o;
  o.x = dx * rstd * g4.x + b4.x;
  o.y = dy * rstd * g4.y + b4.y;
  o.z = dz * rstd * g4.z + b4.z;
  o.w = dw * rstd * g4.w + b4.w;
  st4(h + (size_t)row * D_ + lane * 4, o);
}

// ---------------------------------------------------------------------------
// MFMA GEMM: C[M,N] = op(A[M,K]bf16 @ Bt[N,K]bf16^T + bias) (+R)
// ---------------------------------------------------------------------------
template <bool GELU, bool RES, typename TC>
__global__ __launch_bounds__(256) void mfma_gemm_kernel(
    const bf16* __restrict__ A, const bf16* __restrict__ Bt,
    const float* __restrict__ bias, const TC* __restrict__ Rp, TC* __restrict__ Cp,
    int M, int N, int K) {
  __shared__ __align__(16) char AlsB[128 * 64];
  __shared__ __align__(16) char BlsB[128 * 64];
  const int nb = N >> 7;
  const int bx = blockIdx.x % nb;
  const int by = blockIdx.x / nb;
  const int tid = threadIdx.x;
  const int w = tid >> 6, l = tid & 63;
  const int wm = w >> 1, wn = w & 1;
  const int srow = l >> 2;
  const int kg = (l & 3) ^ ((l >> 3) & 3);
  const bf16* Ag = A + (size_t)(by * 128 + w * 32 + srow) * K + kg * 8;
  const bf16* Bg = Bt + (size_t)(bx * 128 + w * 32 + srow) * K + kg * 8;
  char* AlsW = AlsB + w * 2048;
  char* BlsW = BlsB + w * 2048;
  const int frow = l & 15;
  const int soff = (((l >> 4) ^ ((l >> 1) & 3)) << 4);
  const char* Ar = AlsB + (wm * 64 + frow) * 64 + soff;
  const char* Br = BlsB + (wn * 64 + frow) * 64 + soff;

  f32x4 acc[4][4] = {};
  for (int k0 = 0; k0 < K; k0 += 32) {
    __syncthreads();
    gload_lds16(Ag + k0, AlsW);
    gload_lds16(Ag + (size_t)16 * K + k0, AlsW + 1024);
    gload_lds16(Bg + k0, BlsW);
    gload_lds16(Bg + (size_t)16 * K + k0, BlsW + 1024);
    __syncthreads();
    s16x8 af[4], bfr[4];
#pragma unroll
    for (int mi = 0; mi < 4; ++mi) af[mi] = *(const s16x8*)(Ar + mi * 1024);
#pragma unroll
    for (int nj = 0; nj < 4; ++nj) bfr[nj] = *(const s16x8*)(Br + nj * 1024);
#pragma unroll
    for (int mi = 0; mi < 4; ++mi)
#pragma unroll
      for (int nj = 0; nj < 4; ++nj)
        acc[mi][nj] = __builtin_amdgcn_mfma_f32_16x16x32_bf16(af[mi], bfr[nj],
                                                              acc[mi][nj], 0, 0, 0);
  }
  const int r0 = (l >> 4) << 2;
#pragma unroll
  for (int mi = 0; mi < 4; ++mi) {
    int rowb = by * 128 + wm * 64 + mi * 16 + r0;
#pragma unroll
    for (int r = 0; r < 4; ++r) {
      size_t rowoff = (size_t)(rowb + r) * N;
#pragma unroll
      for (int nj = 0; nj < 4; ++nj) {
        int col = bx * 128 + wn * 64 + nj * 16 + frow;
        float v = acc[mi][nj][r] + bias[col];
        if constexpr (GELU) v = gelu_f(v);
        if constexpr (RES) v += lds1(Rp + rowoff + col);
        sts1(Cp + rowoff + col, v);
      }
    }
  }
}

// Edge head fused: edge_e[row] += sum_col gelu(x@WehT + beh)[row,col] * wef[col]
__global__ __launch_bounds__(256) void edge_head_kernel(
    const bf16* __restrict__ A, const bf16* __restrict__ Bt,
    const float* __restrict__ bias, const float* __restrict__ wef,
    float* __restrict__ edge_e, int M, int N, int K) {
  __shared__ __align__(16) char AlsB[128 * 64];
  __shared__ __align__(16) char BlsB[128 * 64];
  const int nb = N >> 7;
  const int bx = blockIdx.x % nb;
  const int by = blockIdx.x / nb;
  const int tid = threadIdx.x;
  const int w = tid >> 6, l = tid & 63;
  const int wm = w >> 1, wn = w & 1;
  const int srow = l >> 2;
  const int kg = (l & 3) ^ ((l >> 3) & 3);
  const bf16* Ag = A + (size_t)(by * 128 + w * 32 + srow) * K + kg * 8;
  const bf16* Bg = Bt + (size_t)(bx * 128 + w * 32 + srow) * K + kg * 8;
  char* AlsW = AlsB + w * 2048;
  char* BlsW = BlsB + w * 2048;
  const int frow = l & 15;
  const int soff = (((l >> 4) ^ ((l >> 1) & 3)) << 4);
  const char* Ar = AlsB + (wm * 64 + frow) * 64 + soff;
  const char* Br = BlsB + (wn * 64 + frow) * 64 + soff;

  f32x4 acc[4][4] = {};
  for (int k0 = 0; k0 < K; k0 += 32) {
    __syncthreads();
    gload_lds16(Ag + k0, AlsW);
    gload_lds16(Ag + (size_t)16 * K + k0, AlsW + 1024);
    gload_lds16(Bg + k0, BlsW);
    gload_lds16(Bg + (size_t)16 * K + k0, BlsW + 1024);
    __syncthreads();
    s16x8 af[4], bfr[4];
#pragma unroll
    for (int mi = 0; mi < 4; ++mi) af[mi] = *(const s16x8*)(Ar + mi * 1024);
#pragma unroll
    for (int nj = 0; nj < 4; ++nj) bfr[nj] = *(const s16x8*)(Br + nj * 1024);
#pragma unroll
    for (int mi = 0; mi < 4; ++mi)
#pragma unroll
      for (int nj = 0; nj < 4; ++nj)
        acc[mi][nj] = __builtin_amdgcn_mfma_f32_16x16x32_bf16(af[mi], bfr[nj],
                                                              acc[mi][nj], 0, 0, 0);
  }
  const int r0 = (l >> 4) << 2;
#pragma unroll
  for (int mi = 0; mi < 4; ++mi) {
#pragma unroll
    for (int r = 0; r < 4; ++r) {
      float s = 0.f;
#pragma unroll
      for (int nj = 0; nj < 4; ++nj) {
        int col = bx * 128 + wn * 64 + nj * 16 + frow;
        s += gelu_f(acc[mi][nj][r] + bias[col]) * wef[col];
      }
      s += __shfl_xor(s, 1, 64);
      s += __shfl_xor(s, 2, 64);
      s += __shfl_xor(s, 4, 64);
      s += __shfl_xor(s, 8, 64);
      if (frow == 0) {
        int row = by * 128 + wm * 64 + mi * 16 + r0 + r;
        atomicAdd(&edge_e[row], s);
      }
    }
  }
}

// fp32 vector GEMM (small node-head chain only)
template <bool GELU, bool RES>
__global__ __launch_bounds__(256) void vgemm_kernel(
    const float* __restrict__ Ap, const float* __restrict__ Bp,
    const float* __restrict__ bias, const float* __restrict__ Rp,
    float* __restrict__ Cp, int M, int N, int K) {
  __shared__ float As[16][65];
  __shared__ float Bs[16][65];
  int nb = N >> 6;
  int bx = blockIdx.x % nb;
  int by = blockIdx.x / nb;
  int tid = threadIdx.x;
  int tx = tid & 15, ty = tid >> 4;
  int am = tid >> 2, akq = (tid & 3) << 2;
  int bk = tid >> 4, bc = (tid & 15) << 2;
  const float* Ab = Ap + (size_t)(by * 64) * K;
  const float* Bb = Bp + bx * 64;
  float acc[4][4] = {};
  for (int k0 = 0; k0 < K; k0 += 16) {
    float4 av = ld4(Ab + (size_t)am * K + k0 + akq);
    As[akq + 0][am] = av.x; As[akq + 1][am] = av.y;
    As[akq + 2][am] = av.z; As[akq + 3][am] = av.w;
    float4 bv4 = ld4(Bb + (size_t)(k0 + bk) * N + bc);
    Bs[bk][bc + 0] = bv4.x; Bs[bk][bc + 1] = bv4.y;
    Bs[bk][bc + 2] = bv4.z; Bs[bk][bc + 3] = bv4.w;
    __syncthreads();
#pragma unroll
    for (int k = 0; k < 16; ++k) {
      float ar[4], br[4];
#pragma unroll
      for (int i = 0; i < 4; ++i) ar[i] = As[k][ty * 4 + i];
#pragma unroll
      for (int j = 0; j < 4; ++j) br[j] = Bs[k][tx * 4 + j];
#pragma unroll
      for (int i = 0; i < 4; ++i)
#pragma unroll
        for (int j = 0; j < 4; ++j) acc[i][j] += ar[i] * br[j];
    }
    __syncthreads();
  }
#pragma unroll
  for (int i = 0; i < 4; ++i) {
    int row = by * 64 + ty * 4 + i;
    int col0 = bx * 64 + tx * 4;
    float4 v = make_float4(acc[i][0], acc[i][1], acc[i][2], acc[i][3]);
    float4 bs = *(const float4*)(bias + col0);
    v.x += bs.x; v.y += bs.y; v.z += bs.z; v.w += bs.w;
    if constexpr (GELU) {
      v.x = gelu_f(v.x); v.y = gelu_f(v.y); v.z = gelu_f(v.z); v.w = gelu_f(v.w);
    }
    if constexpr (RES) {
      float4 r = ld4(Rp + (size_t)row * N + col0);
      v.x += r.x; v.y += r.y; v.z += r.z; v.w += r.w;
    }
    st4(Cp + (size_t)row * N + col0, v);
  }
}

// ---------------------------------------------------------------------------
// MFMA attention: one wave per (chunk-local atom, head).
// QK^T (16 mfma) -> softmax in C-layout -> P,V^T via swizzled LDS -> PV (16 mfma).
// LDS: P 8KB + Vt 4KB = 12.3KB.
// ---------------------------------------------------------------------------
__global__ __launch_bounds__(64) void attn_kernel(
    const bf16* __restrict__ qkv, const float* __restrict__ cutoff,
    const unsigned char* __restrict__ mask, bf16* __restrict__ out, int atom0) {
  int al = blockIdx.x >> 3;
  int h = blockIdx.x & 7;
  int a = atom0 + al;
  int lane = threadIdx.x;
  __shared__ __align__(16) char Pl[64 * 128];   // P bf16 [64 q-rows][64 j]
  __shared__ __align__(16) char Vt[32 * 128];   // V^T bf16 [32 d][64 j]
  const bf16* base = qkv + (size_t)al * (64 * 768);
  const int fr = lane & 15;           // frag row/col index
  const int kg8 = (lane >> 4) << 3;   // frag k-offset in elements
  const int r0 = (lane >> 4) << 2;    // C/D row base
  // --- Q,K fragments direct from global (k-contiguous rows) ---
  s16x8 qf[4], kf[4];
#pragma unroll
  for (int mi = 0; mi < 4; ++mi)
    qf[mi] = *(const s16x8*)(base + (size_t)(mi * 16 + fr) * 768 + h * 32 + kg8);
#pragma unroll
  for (int nj = 0; nj < 4; ++nj)
    kf[nj] = *(const s16x8*)(base + (size_t)(nj * 16 + fr) * 768 + 256 + h * 32 + kg8);
  // --- stage V^T into LDS (swizzled: byte ^= (d&7)<<4) ---
  {
    int vrow = lane >> 3;          // 0..7
    int d4 = (lane & 7) << 2;      // 0..28
#pragma unroll
    for (int it = 0; it < 8; ++it) {
      int row = it * 8 + vrow;
      u16x4 v = *(const u16x4*)(base + (size_t)row * 768 + 512 + h * 32 + d4);
#pragma unroll
      for (int c = 0; c < 4; ++c) {
        int d = d4 + c;
        int byt = (d * 128 + row * 2) ^ ((d & 7) << 4);
        *(bf16*)(Vt + byt) = v[c];
      }
    }
  }
  // --- QK^T ---
  f32x4 s[4][4];
#pragma unroll
  for (int mi = 0; mi < 4; ++mi)
#pragma unroll
    for (int nj = 0; nj < 4; ++nj) {
      f32x4 z = {0.f, 0.f, 0.f, 0.f};
      s[mi][nj] = __builtin_amdgcn_mfma_f32_16x16x32_bf16(qf[mi], kf[nj], z, 0, 0, 0);
    }
  // --- softmax in C-layout (col j = nj*16+fr is per-lane) ---
  const float inv = 0.17677669529663687f;  // 1/sqrt(32)
  float cwj[4], mskj[4];
#pragma unroll
  for (int nj = 0; nj < 4; ++nj) {
    int j = nj * 16 + fr;
    cwj[nj] = cutoff[(size_t)a * 64 + j];
    mskj[nj] = mask[(size_t)a * 64 + j] ? 1.f : 0.f;
  }
  float rden[4][4];
#pragma unroll
  for (int mi = 0; mi < 4; ++mi) {
    float rm[4] = {-3e38f, -3e38f, -3e38f, -3e38f};
#pragma unroll
    for (int nj = 0; nj < 4; ++nj)
#pragma unroll
      for (int r = 0; r < 4; ++r) {
        float v = s[mi][nj][r] * inv;
        if (mskj[nj] != 0.f) v = -1e9f;
        s[mi][nj][r] = v;
        rm[r] = fmaxf(rm[r], v);
      }
#pragma unroll
    for (int r = 0; r < 4; ++r) {
      rm[r] = fmaxf(rm[r], __shfl_xor(rm[r], 1, 64));
      rm[r] = fmaxf(rm[r], __shfl_xor(rm[r], 2, 64));
      rm[r] = fmaxf(rm[r], __shfl_xor(rm[r], 4, 64));
      rm[r] = fmaxf(rm[r], __shfl_xor(rm[r], 8, 64));
    }
    float dn[4] = {0.f, 0.f, 0.f, 0.f};
#pragma unroll
    for (int nj = 0; nj < 4; ++nj)
#pragma unroll
      for (int r = 0; r < 4; ++r) {
        float e = __expf(s[mi][nj][r] - rm[r]);
        s[mi][nj][r] = e;
        dn[r] += e;
      }
#pragma unroll
    for (int r = 0; r < 4; ++r) {
      dn[r] += __shfl_xor(dn[r], 1, 64);
      dn[r] += __shfl_xor(dn[r], 2, 64);
      dn[r] += __shfl_xor(dn[r], 4, 64);
      dn[r] += __shfl_xor(dn[r], 8, 64);
      rden[mi][r] = dn[r];
    }
    // P = e * cutoff[j] -> LDS bf16, swizzled (byte ^= (row&7)<<4)
#pragma unroll
    for (int nj = 0; nj < 4; ++nj)
#pragma unroll
      for (int r = 0; r < 4; ++r) {
        int row = mi * 16 + r0 + r;
        int byt = (row * 128 + (nj * 16 + fr) * 2) ^ ((row & 7) << 4);
        *(bf16*)(Pl + byt) = f2bf(s[mi][nj][r] * cwj[nj]);
      }
  }
  __syncthreads();
  // --- PV: O[64][32] = P[64][64] @ V[64][32], K split in 2 ---
  s16x8 bfv[2][2];  // [dj][kk]
#pragma unroll
  for (int dj = 0; dj < 2; ++dj)
#pragma unroll
    for (int kk = 0; kk < 2; ++kk) {
      int d = dj * 16 + fr;
      int byt = (d * 128 + (kk * 32 + kg8) * 2) ^ ((d & 7) << 4);
      bfv[dj][kk] = *(const s16x8*)(Vt + byt);
    }
  f32x4 o[4][2] = {};
#pragma unroll
  for (int mi = 0; mi < 4; ++mi) {
#pragma unroll
    for (int kk = 0; kk < 2; ++kk) {
      int row = mi * 16 + fr;
      int byt = (row * 128 + (kk * 32 + kg8) * 2) ^ ((row & 7) << 4);
      s16x8 af = *(const s16x8*)(Pl + byt);
#pragma unroll
      for (int dj = 0; dj < 2; ++dj)
        o[mi][dj] = __builtin_amdgcn_mfma_f32_16x16x32_bf16(af, bfv[dj][kk],
                                                            o[mi][dj], 0, 0, 0);
    }
  }
  // --- scale by 1/denom (rows share (r0,r) indexing with S) and store ---
#pragma unroll
  for (int mi = 0; mi < 4; ++mi) {
#pragma unroll
    for (int r = 0; r < 4; ++r) {
      float scr = __builtin_amdgcn_rcpf(rden[mi][r]);
      int row = mi * 16 + r0 + r;
      bf16* orow = out + (size_t)(al * 64 + row) * D_ + h * 32;
#pragma unroll
      for (int dj = 0; dj < 2; ++dj)
        orow[dj * 16 + fr] = f2bf(o[mi][dj][r] * scr);
    }
  }
}

// pooled[a,:] = sum_n x[a,n,:] * (mask?0:cutoff)
__global__ __launch_bounds__(256) void pooled_kernel(
    const bf16* __restrict__ x, const float* __restrict__ cutoff,
    const unsigned char* __restrict__ mask, float* __restrict__ p0) {
  int a = blockIdx.x, d = threadIdx.x;
  __shared__ float w[64];
  if (d < 64) {
    int t = a * 64 + d;
    w[d] = mask[t] ? 0.f : cutoff[t];
  }
  __syncthreads();
  float acc = 0.f;
  const bf16* xb = x + (size_t)a * 64 * D_ + d;
#pragma unroll 8
  for (int n = 0; n < 64; ++n) acc += bf2f(xb[(size_t)n * D_]) * w[n];
  p0[(size_t)a * D_ + d] = acc;
}

template <typename TA>
__global__ __launch_bounds__(256) void rowdot_kernel(
    const TA* __restrict__ Ap, const float* __restrict__ w,
    const float* __restrict__ biasp, const unsigned char* __restrict__ mask,
    float* __restrict__ outp) {
  int row = blockIdx.x * 4 + (threadIdx.x >> 6);
  int lane = threadIdx.x & 63;
  float4 v = ld4(Ap + (size_t)row * D_ + lane * 4);
  float4 ww = *(const float4*)(w + lane * 4);
  float s = wave_sum(v.x * ww.x + v.y * ww.y + v.z * ww.z + v.w * ww.w);
  if (lane == 0) {
    float e = s + biasp[0];
    if (mask && mask[row]) e = 0.f;
    outp[row] = e;
  }
}

// energies[a] += node_e[a] + sum_n (mask?0:(edge_e+bef)) * cutoff
__global__ __launch_bounds__(64) void accum_energy_kernel(
    const float* __restrict__ node_e, const float* __restrict__ edge_e,
    const float* __restrict__ befp, const unsigned char* __restrict__ mask,
    const float* __restrict__ cutoff, float* __restrict__ energies) {
  int a = blockIdx.x, n = threadIdx.x;
  int t = a * 64 + n;
  float e = mask[t] ? 0.f : (edge_e[t] + befp[0]);
  float s = wave_sum(e * cutoff[t]);
  if (n == 0) energies[a] += node_e[a] + s;
}

__global__ __launch_bounds__(256) void rev_mix_kernel(
    const bf16* __restrict__ x, const int* __restrict__ rev,
    const unsigned char* __restrict__ mask, bf16* __restrict__ msgs) {
  size_t tid = (size_t)blockIdx.x * 256 + threadIdx.x;
  int token = int(tid >> 6);
  int d4 = int(tid & 63) << 2;
  int src = rev[token];
  float4 r = make_float4(0.f, 0.f, 0.f, 0.f);
  if (!mask[token] && !mask[src]) r = ld4(x + (size_t)src * D_ + d4);
  float4 m = ld4(msgs + (size_t)token * D_ + d4);
  m.x = 0.5f * (m.x + r.x);
  m.y = 0.5f * (m.y + r.y);
  m.z = 0.5f * (m.z + r.z);
  m.w = 0.5f * (m.w + r.w);
  st4(msgs + (size_t)token * D_ + d4, m);
}

extern "C" void kernel_launch(void* const* d_in, const int* in_sizes, int n_in,
                              void* d_out, int out_size, void* d_ws, size_t ws_size,
                              hipStream_t stream) {
  const int* species = (const int*)d_in[0];
  const int* nspecies = (const int*)d_in[1];
  const float* ev = (const float*)d_in[2];
  const float* ed = (const float*)d_in[3];
  const unsigned char* mask = (const unsigned char*)d_in[4];
  const int* rev = (const int*)d_in[5];
  const float* cutoff = (const float*)d_in[6];
  const float* node_embed = (const float*)d_in[7];
  const float* neigh_embed = (const float*)d_in[8];
  const float* W_edge = (const float*)d_in[9];
  const float* b_edge = (const float*)d_in[10];
  const float* ln1_g = (const float*)d_in[11];
  const float* ln1_b = (const float*)d_in[12];
  const float* Wqkv = (const float*)d_in[13];
  const float* bqkv = (const float*)d_in[14];
  const float* Wo = (const float*)d_in[15];
  const float* bo = (const float*)d_in[16];
  const float* ln2_g = (const float*)d_in[17];
  const float* ln2_b = (const float*)d_in[18];
  const float* Wff1 = (const float*)d_in[19];
  const float* bff1 = (const float*)d_in[20];
  const float* Wff2 = (const float*)d_in[21];
  const float* bff2 = (const float*)d_in[22];
  const float* Wnode = (const float*)d_in[23];
  const float* bnode = (const float*)d_in[24];
  const float* Wnh = (const float*)d_in[25];
  const float* bnh = (const float*)d_in[26];
  const float* Wnf = (const float*)d_in[27];
  const float* bnf = (const float*)d_in[28];
  const float* Weh = (const float*)d_in[29];
  const float* beh = (const float*)d_in[30];
  const float* Wef = (const float*)d_in[31];
  const float* bef = (const float*)d_in[32];
  float* out = (float*)d_out;

  // adaptive chunk count (exact footprints: CH2=308MB, CH4=224MB, CH8=182MB)
  int CHv = 8;
  if (ws_size >= (size_t)330000000) CHv = 2;
  else if (ws_size >= (size_t)240000000) CHv = 4;
  const int RW = AN_ / CHv;    // tokens per chunk
  const int ATC = A_ / CHv;    // atoms per chunk

  char* wsb = (char*)d_ws;
  size_t off = 0;
  auto alloc = [&](size_t bytes) {
    void* p = wsb + off;
    off += (bytes + 255) & ~(size_t)255;
    return p;
  };
  bf16* msgs = (bf16*)alloc((size_t)AN_ * D_ * 2);     // 67 MB
  bf16* x = (bf16*)alloc((size_t)AN_ * D_ * 2);        // 67 MB
  bf16* U1 = (bf16*)alloc((size_t)RW * D_ * 2);        // h / attn-out chunk
  bf16* U2 = (bf16*)alloc((size_t)RW * 1024 * 2);      // qkv / ff-hidden chunk
  bf16* WqkvT = (bf16*)alloc((size_t)L_ * 768 * 256 * 2);
  bf16* WoT = (bf16*)alloc((size_t)L_ * 256 * 256 * 2);
  bf16* Wff1T = (bf16*)alloc((size_t)L_ * 1024 * 256 * 2);
  bf16* Wff2T = (bf16*)alloc((size_t)L_ * 256 * 1024 * 2);
  bf16* WehT = (bf16*)alloc((size_t)L_ * 256 * 256 * 2);
  float* nodesbuf = (float*)alloc((size_t)A_ * D_ * 4);
  float* node_e = (float*)alloc((size_t)A_ * 4);
  float* edge_e = (float*)alloc((size_t)AN_ * 4);
  // node-head scratch aliased into U2 (dead during node-head phase)
  float* p0 = (float*)U2;
  float* p1 = p0 + (size_t)A_ * D_;
  float* p2 = p1 + (size_t)A_ * D_;
  (void)in_sizes; (void)n_in; (void)out_size;

  for (int l = 0; l < L_; ++l) {
    wt_kernel<<<(256 * 768 + 255) / 256, 256, 0, stream>>>(
        Wqkv + (size_t)l * 256 * 768, WqkvT + (size_t)l * 768 * 256, 256, 768);
    wt_kernel<<<(256 * 256 + 255) / 256, 256, 0, stream>>>(
        Wo + (size_t)l * 256 * 256, WoT + (size_t)l * 256 * 256, 256, 256);
    wt_kernel<<<(256 * 1024 + 255) / 256, 256, 0, stream>>>(
        Wff1 + (size_t)l * 256 * 1024, Wff1T + (size_t)l * 1024 * 256, 256, 1024);
    wt_kernel<<<(1024 * 256 + 255) / 256, 256, 0, stream>>>(
        Wff2 + (size_t)l * 1024 * 256, Wff2T + (size_t)l * 256 * 1024, 1024, 256);
    wt_kernel<<<(256 * 256 + 255) / 256, 256, 0, stream>>>(
        Weh + (size_t)l * 256 * 256, WehT + (size_t)l * 256 * 256, 256, 256);
  }

  zero_kernel<<<(A_ + 255) / 256, 256, 0, stream>>>(out, A_);
  init_msgs_kernel<<<AN_, 256, 0, stream>>>(nspecies, neigh_embed, msgs);

  for (int l = 0; l < L_; ++l) {
    gather_nodes_kernel<<<A_, 256, 0, stream>>>(
        species, node_embed + (size_t)l * V_ * D_, nodesbuf);
    // --- attention block (chunked; build_x + LN1 fused per chunk) ---
    for (int c = 0; c < CHv; ++c) {
      bf16* xc = x + (size_t)c * RW * D_;
      build_x_ln_kernel<<<RW / 4, 256, 0, stream>>>(
          msgs, ev, ed, W_edge + (size_t)l * 4 * D_, b_edge + (size_t)l * D_,
          nodesbuf, ln1_g + (size_t)l * D_, ln1_b + (size_t)l * D_,
          xc, U1, c * RW);
      mfma_gemm_kernel<false, false, bf16><<<(RW / 128) * (768 / 128), 256, 0, stream>>>(
          U1, WqkvT + (size_t)l * 768 * 256, bqkv + (size_t)l * 768, (const bf16*)nullptr,
          U2, RW, 768, 256);
      attn_kernel<<<ATC * H_, 64, 0, stream>>>(U2, cutoff, mask, U1, c * ATC);
      mfma_gemm_kernel<false, true, bf16><<<(RW / 128) * (256 / 128), 256, 0, stream>>>(
          U1, WoT + (size_t)l * 256 * 256, bo + (size_t)l * D_, xc, xc, RW, 256, 256);
    }
    // --- FF block (chunked) ---
    for (int c = 0; c < CHv; ++c) {
      bf16* xc = x + (size_t)c * RW * D_;
      ln_apply_kernel<<<RW / 4, 256, 0, stream>>>(
          xc, ln2_g + (size_t)l * D_, ln2_b + (size_t)l * D_, U1);
      mfma_gemm_kernel<true, false, bf16><<<(RW / 128) * (1024 / 128), 256, 0, stream>>>(
          U1, Wff1T + (size_t)l * 1024 * 256, bff1 + (size_t)l * 1024, (const bf16*)nullptr,
          U2, RW, 1024, 256);
      mfma_gemm_kernel<false, true, bf16><<<(RW / 128) * (256 / 128), 256, 0, stream>>>(
          U2, Wff2T + (size_t)l * 256 * 1024, bff2 + (size_t)l * D_, xc, xc,
          RW, 256, 1024);
    }
    // --- node pooling + node energy head (f32 vector, small; scratch in U2) ---
    pooled_kernel<<<A_, 256, 0, stream>>>(x, cutoff, mask, p0);
    vgemm_kernel<false, true><<<(A_ / 64) * (256 / 64), 256, 0, stream>>>(
        p0, Wnode + (size_t)l * D_ * D_, bnode + (size_t)l * D_, nodesbuf, p1,
        A_, 256, 256);
    vgemm_kernel<true, false><<<(A_ / 64) * (256 / 64), 256, 0, stream>>>(
        p1, Wnh + (size_t)l * D_ * D_, bnh + (size_t)l * D_, nullptr, p2, A_, 256, 256);
    rowdot_kernel<float><<<A_ / 4, 256, 0, stream>>>(
        p2, Wnf + (size_t)l * D_, bnf + l, nullptr, node_e);
    // --- edge energy head: fused GEMM+dot, one dispatch over full x ---
    zero_kernel<<<(AN_ + 255) / 256, 256, 0, stream>>>(edge_e, AN_);
    edge_head_kernel<<<(AN_ / 128) * (256 / 128), 256, 0, stream>>>(
        x, WehT + (size_t)l * 256 * 256, beh + (size_t)l * D_, Wef + (size_t)l * D_,
        edge_e, AN_, 256, 256);
    accum_energy_kernel<<<A_, 64, 0, stream>>>(node_e, edge_e, bef + l, mask, cutoff, out);
    // --- reverse message mixing ---
    rev_mix_kernel<<<AN_ * 64 / 256, 256, 0, stream>>>(x, rev, mask, msgs);
  }
}